// Round 3
// baseline (2436.463 us; speedup 1.0000x reference)
//
#include <hip/hip_runtime.h>

// EquiConv fully-fused pipeline (round 4).
// E = 200000, MUL_S = 128, MUL_V = 64, FC_IN = 128, FC_HID = 64, LEN_W = 192.
//
// lane = edge (64 lanes = 64 edges/block), wave = column slice; 8 waves/block.
// KEY CHANGE vs round 3: weights are loaded via VMEM broadcast
// (global_load_dwordx4 with wave-uniform address -- wid deliberately NOT
// readfirstlane'd, so the compiler cannot scalarize to s_load). SMEM s_load
// forced an un-counted lgkmcnt(0) drain every k-iteration (SMEM returns out
// of order); VMEM uses counted vmcnt waits -> load(k+1) overlaps fma(k).
// x activations stay in LDS (coalesced staging, float4-aligned pitches,
// b128 reads/writes -> no bank conflicts). S2 accumulates directly into the
// x2s-scaled S1 registers (-24 accumulators, register wall is the occupancy cap).
//
// LDS (12544 floats = 50176 B), phase-aliased:
//   S  = [0, 8448)  : [64][132] x1s tile, then fea_w tile; then h1 in [0,4096)
//   H0 = [8448,12544): h0 [64 cols][64 edges]
//   vec phase: whole lds = [64][196] x1v tile
//
// ws layout (floats):
//   [0)      Wbig 128x256 = [w1_p0|w1_p1|w1_p2] cols pre-scaled (w2_*, INV_S, SQ2)
//   [32768)  Wd   64x192  = [w1_p4|w1_p5] cols pre-scaled (w2_*, INV_V, SQ3, SQ2)
//   [45056)  Wp3  64x64   = w1_p3 cols pre-scaled (w2_p3, INV_V, SQ2)

#define FMA4(P, X, W) { (P)[0] = fmaf((X), (W).x, (P)[0]); \
                        (P)[1] = fmaf((X), (W).y, (P)[1]); \
                        (P)[2] = fmaf((X), (W).z, (P)[2]); \
                        (P)[3] = fmaf((X), (W).w, (P)[3]); }

__device__ __forceinline__ float sigmoidf_(float x) { return 1.0f / (1.0f + __expf(-x)); }

// ---------------------------------------------------------------- prep
__global__ __launch_bounds__(256) void prep_weights(
    const float* __restrict__ w1_p0, const float* __restrict__ w2_p0,
    const float* __restrict__ w1_p1, const float* __restrict__ w2_p1,
    const float* __restrict__ w1_p2, const float* __restrict__ w2_p2,
    const float* __restrict__ w1_p3, const float* __restrict__ w2_p3,
    const float* __restrict__ w1_p4, const float* __restrict__ w2_p4,
    const float* __restrict__ w1_p5, const float* __restrict__ w2_p5,
    float* __restrict__ Wbig, float* __restrict__ Wd, float* __restrict__ Wp3)
{
    const float INV_S = 0.08838834764831845f;   // 1/sqrt(128)
    const float INV_V = 0.125f;                 // 1/sqrt(64)
    const float SQ2   = 0.7071067811865476f;
    const float SQ3   = 0.5773502691896258f;
    int gid = blockIdx.x * 256 + threadIdx.x;
    if (gid < 128*256) {
        int k = gid >> 8, c = gid & 255;
        float v;
        if (c < 128)      v = w1_p0[k*128 + c]       * w2_p0[c]       * (INV_S*SQ2);
        else if (c < 192) v = w1_p1[k*64 + (c-128)]  * w2_p1[c-128]   * (INV_S*SQ2);
        else              v = w1_p2[k*64 + (c-192)]  * w2_p2[c-192]   * (INV_S*SQ2);
        Wbig[gid] = v;
    } else if (gid < 128*256 + 64*192) {
        int g = gid - 128*256;
        int u = g / 192, c = g - u*192;
        float v;
        if (c < 128) v = w1_p4[u*128 + c]        * w2_p4[c]     * (INV_V*SQ3*SQ2);
        else         v = w1_p5[u*64 + (c-128)]   * w2_p5[c-128] * (INV_V*SQ3*SQ2);
        Wd[g] = v;
    } else if (gid < 128*256 + 64*192 + 64*64) {
        int g = gid - (128*256 + 64*192);
        int w = g & 63;
        Wp3[g] = w1_p3[g] * w2_p3[w] * (INV_V*SQ2);
    }
}

// ---------------------------------------------------------------- fused
__global__ __launch_bounds__(512) void fused_kernel(
    const float* __restrict__ fea_in1, const float* __restrict__ fea_in2,
    const float* __restrict__ fea_w,
    const float* __restrict__ fc_w0, const float* __restrict__ fc_b0,
    const float* __restrict__ fc_w1, const float* __restrict__ fc_b1,
    const float* __restrict__ fc_w2, const float* __restrict__ fc_b2,
    const float* __restrict__ Wbig, const float* __restrict__ Wd,
    const float* __restrict__ Wp3,
    float* __restrict__ out)
{
    __shared__ float lds[12544];          // 50176 B
    float* S  = lds;                      // [64][132] staging tile
    float* H0 = lds + 8448;               // h0 [64 cols][64 edges]
    float* H1 = lds;                      // h1 [64 cols][64 edges] (aliases S head)

    const int t   = threadIdx.x;
    const int l   = t & 63;               // lane = edge-in-block
    const int wid = t >> 6;               // wave id 0..7 -- NOT readfirstlane'd:
                                          // keeps weight addrs "divergent" -> VMEM
    const long e0b = (long)blockIdx.x * 64;
    const long e   = e0b + l;

    // ---- stage x1s tile (coalesced b128) -> S[e][k], pitch 132
    #pragma unroll
    for (int r = 0; r < 4; ++r) {
        int f = t + r*512;                // 2048 float4 = 64x128
        int ee = f >> 5, c4 = f & 31;
        float4 v = *(const float4*)(fea_in1 + (e0b + ee)*320 + c4*4);
        *(float4*)(&S[ee*132 + c4*4]) = v;
    }
    // ---- prefetch fea_w tile into regs (written to LDS after S1)
    float4 fwst[4];
    #pragma unroll
    for (int r = 0; r < 4; ++r) {
        int f = t + r*512;
        int ee = f >> 5, c4 = f & 31;
        fwst[r] = *(const float4*)(fea_w + (e0b + ee)*128 + c4*4);
    }
    float4 x2r = *(const float4*)(fea_in2 + e*4);
    __syncthreads();

    // ---------------- S1 = x1s @ Wbig; 16 scal + 8 gate + 8 vcoef cols, K=128
    float aS[16], aG[8], aV[8];
    #pragma unroll
    for (int j = 0; j < 16; ++j) aS[j] = 0.f;
    #pragma unroll
    for (int j = 0; j < 8; ++j) { aG[j] = 0.f; aV[j] = 0.f; }
    {
        const float4* xrow = (const float4*)(S + l*132);
        for (int kc = 0; kc < 32; ++kc) {
            float4 x4 = xrow[kc];
            float xs[4] = {x4.x, x4.y, x4.z, x4.w};
            #pragma unroll
            for (int kk = 0; kk < 4; ++kk) {
                const float4* wb = (const float4*)Wbig + (kc*4 + kk)*64;
                float4 ws0 = wb[wid*4 + 0];
                float4 ws1 = wb[wid*4 + 1];
                float4 ws2 = wb[wid*4 + 2];
                float4 ws3 = wb[wid*4 + 3];
                float4 wg0 = wb[32 + wid*2 + 0];
                float4 wg1 = wb[32 + wid*2 + 1];
                float4 wv0 = wb[48 + wid*2 + 0];
                float4 wv1 = wb[48 + wid*2 + 1];
                const float x = xs[kk];
                FMA4(aS + 0,  x, ws0);
                FMA4(aS + 4,  x, ws1);
                FMA4(aS + 8,  x, ws2);
                FMA4(aS + 12, x, ws3);
                FMA4(aG + 0,  x, wg0);
                FMA4(aG + 4,  x, wg1);
                FMA4(aV + 0,  x, wv0);
                FMA4(aV + 4,  x, wv1);
            }
        }
    }
    // fold x2s now; the vec phase accumulates S2 directly into aS/aG
    const float x2s = x2r.x;
    #pragma unroll
    for (int j = 0; j < 16; ++j) aS[j] *= x2s;
    #pragma unroll
    for (int j = 0; j < 8; ++j)  aG[j] *= x2s;
    __syncthreads();                               // all x1s reads done

    // ---- write fea_w tile into S (b128, pitch 132)
    #pragma unroll
    for (int r = 0; r < 4; ++r) {
        int f = t + r*512;
        int ee = f >> 5, c4 = f & 31;
        *(float4*)(&S[ee*132 + c4*4]) = fwst[r];
    }
    __syncthreads();

    // ---------------- FC layer 0: h0 = silu(fw @ w0 + b0); 8 cols, K=128
    float ha[8];
    {
        const float4* bb = (const float4*)fc_b0;
        float4 b0 = bb[wid*2 + 0], b1 = bb[wid*2 + 1];
        ha[0]=b0.x; ha[1]=b0.y; ha[2]=b0.z; ha[3]=b0.w;
        ha[4]=b1.x; ha[5]=b1.y; ha[6]=b1.z; ha[7]=b1.w;
        const float4* xrow = (const float4*)(S + l*132);
        for (int kc = 0; kc < 32; ++kc) {
            float4 x4 = xrow[kc];
            float xs[4] = {x4.x, x4.y, x4.z, x4.w};
            #pragma unroll
            for (int kk = 0; kk < 4; ++kk) {
                const float4* wb = (const float4*)fc_w0 + (kc*4 + kk)*16;
                float4 w0 = wb[wid*2 + 0];
                float4 w1 = wb[wid*2 + 1];
                FMA4(ha + 0, xs[kk], w0);
                FMA4(ha + 4, xs[kk], w1);
            }
        }
    }
    #pragma unroll
    for (int j = 0; j < 8; ++j) {
        float z = ha[j];
        H0[(wid*8 + j)*64 + l] = z * sigmoidf_(z);
    }
    __syncthreads();                               // h0 ready; fw reads done

    // ---------------- FC layer 1: h1 = silu(h0 @ w1 + b1); 8 cols, K=64
    {
        const float4* bb = (const float4*)fc_b1;
        float4 b0 = bb[wid*2 + 0], b1 = bb[wid*2 + 1];
        ha[0]=b0.x; ha[1]=b0.y; ha[2]=b0.z; ha[3]=b0.w;
        ha[4]=b1.x; ha[5]=b1.y; ha[6]=b1.z; ha[7]=b1.w;
        #pragma unroll 4
        for (int k = 0; k < 64; ++k) {
            float x = H0[k*64 + l];                // bank l%32: 2-way, free
            const float4* wb = (const float4*)fc_w1 + k*16;
            float4 w0 = wb[wid*2 + 0];
            float4 w1 = wb[wid*2 + 1];
            FMA4(ha + 0, x, w0);
            FMA4(ha + 4, x, w1);
        }
    }
    #pragma unroll
    for (int j = 0; j < 8; ++j) {
        float z = ha[j];
        H1[(wid*8 + j)*64 + l] = z * sigmoidf_(z); // into S head (fw dead)
    }
    __syncthreads();                               // h1 ready

    // ---------------- FC layer 2: W = h1 @ w2 + b2; 16 scal + 8 gate cols, K=64
    float aWs[16], aWg[8];
    {
        const float4* bb = (const float4*)fc_b2;
        #pragma unroll
        for (int q = 0; q < 4; ++q) {
            float4 b = bb[wid*4 + q];
            aWs[q*4+0]=b.x; aWs[q*4+1]=b.y; aWs[q*4+2]=b.z; aWs[q*4+3]=b.w;
        }
        #pragma unroll
        for (int q = 0; q < 2; ++q) {
            float4 b = bb[32 + wid*2 + q];
            aWg[q*4+0]=b.x; aWg[q*4+1]=b.y; aWg[q*4+2]=b.z; aWg[q*4+3]=b.w;
        }
        #pragma unroll 2
        for (int k = 0; k < 64; ++k) {
            float x = H1[k*64 + l];
            const float4* wb = (const float4*)fc_w2 + k*48;
            float4 w0 = wb[wid*4 + 0];
            float4 w1 = wb[wid*4 + 1];
            float4 w2 = wb[wid*4 + 2];
            float4 w3 = wb[wid*4 + 3];
            float4 g0 = wb[32 + wid*2 + 0];
            float4 g1 = wb[32 + wid*2 + 1];
            FMA4(aWs + 0,  x, w0);
            FMA4(aWs + 4,  x, w1);
            FMA4(aWs + 8,  x, w2);
            FMA4(aWs + 12, x, w3);
            FMA4(aWg + 0,  x, g0);
            FMA4(aWg + 4,  x, g1);
        }
    }

    // ---- stage x1v tile: loads issued before the barrier, LDS writes after
    float4 xvst[6];
    #pragma unroll
    for (int r = 0; r < 6; ++r) {
        int f = t + r*512;                // 3072 float4 = 64x192
        int ee = f / 48, c4 = f - ee*48;
        xvst[r] = *(const float4*)(fea_in1 + (e0b + ee)*320 + 128 + c4*4);
    }
    __syncthreads();                               // h1 reads done
    #pragma unroll
    for (int r = 0; r < 6; ++r) {
        int f = t + r*512;
        int ee = f / 48, c4 = f - ee*48;
        *(float4*)(&lds[ee*196 + c4*4]) = xvst[r]; // [64][196], b128-aligned
    }
    __syncthreads();

    // ---------------- vec branch: A3 (8w x 3i) + S2 accumulated into aS/aG, K=64
    const float c1 = x2r.y, c2 = x2r.z, c3 = x2r.w;
    float aA3[8][3];
    #pragma unroll
    for (int j = 0; j < 8; ++j) { aA3[j][0]=0.f; aA3[j][1]=0.f; aA3[j][2]=0.f; }
    {
        const float4* vrow = (const float4*)(lds + l*196);
        for (int uq = 0; uq < 16; ++uq) {
            float4 q0 = vrow[uq*3 + 0];
            float4 q1 = vrow[uq*3 + 1];
            float4 q2 = vrow[uq*3 + 2];
            float arr[12] = {q0.x,q0.y,q0.z,q0.w, q1.x,q1.y,q1.z,q1.w,
                             q2.x,q2.y,q2.z,q2.w};
            #pragma unroll
            for (int m = 0; m < 4; ++m) {
                const int u = uq*4 + m;
                const float v0 = arr[m*3+0], v1 = arr[m*3+1], v2 = arr[m*3+2];
                const float4* wp = (const float4*)Wp3 + u*16;
                float4 p0 = wp[wid*2 + 0];
                float4 p1 = wp[wid*2 + 1];
                #pragma unroll
                for (int i4 = 0; i4 < 4; ++i4) {
                    const float w0 = (&p0.x)[i4];
                    const float w1 = (&p1.x)[i4];
                    aA3[i4][0]   = fmaf(v0, w0, aA3[i4][0]);
                    aA3[i4][1]   = fmaf(v1, w0, aA3[i4][1]);
                    aA3[i4][2]   = fmaf(v2, w0, aA3[i4][2]);
                    aA3[4+i4][0] = fmaf(v0, w1, aA3[4+i4][0]);
                    aA3[4+i4][1] = fmaf(v1, w1, aA3[4+i4][1]);
                    aA3[4+i4][2] = fmaf(v2, w1, aA3[4+i4][2]);
                }
                const float du = fmaf(v0, c1, fmaf(v1, c2, v2*c3));
                const float4* wd = (const float4*)Wd + u*48;
                float4 d0 = wd[wid*4 + 0];
                float4 d1 = wd[wid*4 + 1];
                float4 d2 = wd[wid*4 + 2];
                float4 d3 = wd[wid*4 + 3];
                float4 dg0 = wd[32 + wid*2 + 0];
                float4 dg1 = wd[32 + wid*2 + 1];
                FMA4(aS + 0,  du, d0);
                FMA4(aS + 4,  du, d1);
                FMA4(aS + 8,  du, d2);
                FMA4(aS + 12, du, d3);
                FMA4(aG + 0,  du, dg0);
                FMA4(aG + 4,  du, dg1);
            }
        }
    }

    // ---------------- epilogue: all in registers, direct stores
    float* orow = out + e*320;
    const int sc0 = wid * 16;
    const int wv0 = wid * 8;
    #pragma unroll
    for (int q = 0; q < 4; ++q) {
        float o[4];
        #pragma unroll
        for (int r = 0; r < 4; ++r) {
            const int j = q*4 + r;
            float s = aS[j];                       // = S1*x2s + S2
            o[r] = s * sigmoidf_(s) * aWs[j];
        }
        *(float4*)(orow + sc0 + q*4) = make_float4(o[0], o[1], o[2], o[3]);
    }
    float x2v[3] = {c1, c2, c3};
    float vo[24];
    #pragma unroll
    for (int j = 0; j < 8; ++j) {
        float g  = aG[j];                          // = G1*x2s + G2
        float sg = sigmoidf_(g) * aWg[j];
        #pragma unroll
        for (int i = 0; i < 3; ++i)
            vo[j*3 + i] = sg * fmaf(aV[j], x2v[i], aA3[j][i] * x2s);
    }
    #pragma unroll
    for (int q = 0; q < 6; ++q)
        *(float4*)(orow + 128 + wv0*3 + q*4) =
            make_float4(vo[q*4], vo[q*4+1], vo[q*4+2], vo[q*4+3]);
}

// ---------------------------------------------------------------- launch
extern "C" void kernel_launch(void* const* d_in, const int* in_sizes, int n_in,
                              void* d_out, int out_size, void* d_ws, size_t ws_size,
                              hipStream_t stream) {
    const float* fea_in1 = (const float*)d_in[0];
    const float* fea_in2 = (const float*)d_in[1];
    const float* fea_w   = (const float*)d_in[2];
    // d_in[3] = batch_edge (unused by reference)
    const float* w1_p0 = (const float*)d_in[4];
    const float* w2_p0 = (const float*)d_in[5];
    const float* w1_p1 = (const float*)d_in[6];
    const float* w2_p1 = (const float*)d_in[7];
    const float* w1_p2 = (const float*)d_in[8];
    const float* w2_p2 = (const float*)d_in[9];
    const float* w1_p3 = (const float*)d_in[10];
    const float* w2_p3 = (const float*)d_in[11];
    const float* w1_p4 = (const float*)d_in[12];
    const float* w2_p4 = (const float*)d_in[13];
    const float* w1_p5 = (const float*)d_in[14];
    const float* w2_p5 = (const float*)d_in[15];
    const float* fc_w0 = (const float*)d_in[16];
    const float* fc_b0 = (const float*)d_in[17];
    const float* fc_w1 = (const float*)d_in[18];
    const float* fc_b1 = (const float*)d_in[19];
    const float* fc_w2 = (const float*)d_in[20];
    const float* fc_b2 = (const float*)d_in[21];

    const int E = in_sizes[0] / 320;   // 200000

    float* ws   = (float*)d_ws;
    float* Wbig = ws;                  // 32768 floats
    float* Wd   = ws + 32768;          // 12288 floats
    float* Wp3  = ws + 45056;          // 4096 floats
    float* out  = (float*)d_out;

    prep_weights<<<192, 256, 0, stream>>>(w1_p0, w2_p0, w1_p1, w2_p1, w1_p2, w2_p2,
                                          w1_p3, w2_p3, w1_p4, w2_p4, w1_p5, w2_p5,
                                          Wbig, Wd, Wp3);
    fused_kernel<<<E/64, 512, 0, stream>>>(fea_in1, fea_in2, fea_w,
                                           fc_w0, fc_b0, fc_w1, fc_b1, fc_w2, fc_b2,
                                           Wbig, Wd, Wp3, out);
}

// Round 4
// 1321.874 us; speedup vs baseline: 1.8432x; 1.8432x over previous
//
#include <hip/hip_runtime.h>

// EquiConv fully-fused pipeline (round 5).
// E = 200000, MUL_S = 128, MUL_V = 64, FC_IN = 128, FC_HID = 64, LEN_W = 192.
//
// Base = round-2 structure (790 us, verified): lane = edge, wave = column
// slice, 8 waves/block, activations staged in LDS (scalar writes, odd pitch,
// conflict-free reads), weights wave-uniform.
// CHANGE: weight streams are SPLIT across the scalar and vector memory pipes.
//   - Round 2 (all SMEM): K$ MSHR saturation + lgkmcnt(0) drains -> 37% VALU.
//   - Round 3 (all VMEM): compiler hoisted ~128 VGPRs of in-flight loads ->
//     accumulator spills (WRITE_SIZE 251->500 MB) -> 14% VALU.
//   - Now: per k, scal stream (16 floats) via SMEM (s_load_dwordx16, 1/3 of
//     round-2's miss rate), gate/vcoef streams via VMEM dwordx4 with a
//     non-readfirstlane'd wave id (widv) so they ride the deep vmcnt queue.
//     Unroll 2 keeps in-flight VMEM <= ~32 VGPRs.
// Also kept from round 3 (both verified): x2s folded into aS/aG so the vec
// phase accumulates S2 in-place (-24 regs), and the late x1v staging window.
//
// ws layout (floats):
//   [0)      Wbig 128x256 = [w1_p0|w1_p1|w1_p2] cols pre-scaled (w2_*, INV_S, SQ2)
//   [32768)  Wd   64x192  = [w1_p4|w1_p5] cols pre-scaled (w2_*, INV_V, SQ3, SQ2)
//   [45056)  Wp3  64x64   = w1_p3 cols pre-scaled (w2_p3, INV_V, SQ2)

#define FMA4(P, X, W) { (P)[0] = fmaf((X), (W).x, (P)[0]); \
                        (P)[1] = fmaf((X), (W).y, (P)[1]); \
                        (P)[2] = fmaf((X), (W).z, (P)[2]); \
                        (P)[3] = fmaf((X), (W).w, (P)[3]); }

__device__ __forceinline__ float sigmoidf_(float x) { return 1.0f / (1.0f + __expf(-x)); }

// ---------------------------------------------------------------- prep
__global__ __launch_bounds__(256) void prep_weights(
    const float* __restrict__ w1_p0, const float* __restrict__ w2_p0,
    const float* __restrict__ w1_p1, const float* __restrict__ w2_p1,
    const float* __restrict__ w1_p2, const float* __restrict__ w2_p2,
    const float* __restrict__ w1_p3, const float* __restrict__ w2_p3,
    const float* __restrict__ w1_p4, const float* __restrict__ w2_p4,
    const float* __restrict__ w1_p5, const float* __restrict__ w2_p5,
    float* __restrict__ Wbig, float* __restrict__ Wd, float* __restrict__ Wp3)
{
    const float INV_S = 0.08838834764831845f;   // 1/sqrt(128)
    const float INV_V = 0.125f;                 // 1/sqrt(64)
    const float SQ2   = 0.7071067811865476f;
    const float SQ3   = 0.5773502691896258f;
    int gid = blockIdx.x * 256 + threadIdx.x;
    if (gid < 128*256) {
        int k = gid >> 8, c = gid & 255;
        float v;
        if (c < 128)      v = w1_p0[k*128 + c]       * w2_p0[c]       * (INV_S*SQ2);
        else if (c < 192) v = w1_p1[k*64 + (c-128)]  * w2_p1[c-128]   * (INV_S*SQ2);
        else              v = w1_p2[k*64 + (c-192)]  * w2_p2[c-192]   * (INV_S*SQ2);
        Wbig[gid] = v;
    } else if (gid < 128*256 + 64*192) {
        int g = gid - 128*256;
        int u = g / 192, c = g - u*192;
        float v;
        if (c < 128) v = w1_p4[u*128 + c]        * w2_p4[c]     * (INV_V*SQ3*SQ2);
        else         v = w1_p5[u*64 + (c-128)]   * w2_p5[c-128] * (INV_V*SQ3*SQ2);
        Wd[g] = v;
    } else if (gid < 128*256 + 64*192 + 64*64) {
        int g = gid - (128*256 + 64*192);
        int w = g & 63;
        Wp3[g] = w1_p3[g] * w2_p3[w] * (INV_V*SQ2);
    }
}

// ---------------------------------------------------------------- fused
__global__ __launch_bounds__(512) void fused_kernel(
    const float* __restrict__ fea_in1, const float* __restrict__ fea_in2,
    const float* __restrict__ fea_w,
    const float* __restrict__ fc_w0, const float* __restrict__ fc_b0,
    const float* __restrict__ fc_w1, const float* __restrict__ fc_b1,
    const float* __restrict__ fc_w2, const float* __restrict__ fc_b2,
    const float* __restrict__ Wbig, const float* __restrict__ Wd,
    const float* __restrict__ Wp3,
    float* __restrict__ out)
{
    __shared__ float lds[12352];          // 49408 B
    float* S = lds;                       // [64][129] pitch-129 tile (8256 floats)
    float* H = lds + 8256;                // h0 [64 cols][64 edges] (4096 floats)

    const int t    = threadIdx.x;
    const int l    = t & 63;                                  // lane = edge
    const int widu = __builtin_amdgcn_readfirstlane(t >> 6);  // uniform -> SMEM
    const int widv = t >> 6;                                  // "divergent" -> VMEM
    const int sc0u = widu * 16;   // scal-col base (SMEM streams)
    const int wv0u = widu * 8;    // w-index base  (SMEM streams)
    const long e0b = (long)blockIdx.x * 64;
    const long e   = e0b + l;

    // ---- stage x1s tile (coalesced loads, scalar LDS writes) -> S[e][k], pitch 129
    #pragma unroll
    for (int r = 0; r < 4; ++r) {
        int f = t + r*512;                // 2048 float4 = 64x128
        int ee = f >> 5, c4 = f & 31;
        float4 v = *(const float4*)(fea_in1 + (e0b + ee)*320 + c4*4);
        float* d = &S[ee*129 + c4*4];
        d[0] = v.x; d[1] = v.y; d[2] = v.z; d[3] = v.w;
    }
    // ---- prefetch fea_w tile into regs (written to LDS after S1)
    float4 fwst[4];
    #pragma unroll
    for (int r = 0; r < 4; ++r) {
        int f = t + r*512;
        int ee = f >> 5, c4 = f & 31;
        fwst[r] = *(const float4*)(fea_w + (e0b + ee)*128 + c4*4);
    }
    float4 x2r = *(const float4*)(fea_in2 + e*4);
    __syncthreads();

    // ---------------- S1 = x1s @ Wbig; 16 scal + 8 gate + 8 vcoef cols, K=128
    // scal via SMEM (1 s_load_dwordx16/k), gate+vcoef via VMEM (4 dwordx4/k)
    float aS[16], aG[8], aV[8];
    #pragma unroll
    for (int j = 0; j < 16; ++j) aS[j] = 0.f;
    #pragma unroll
    for (int j = 0; j < 8; ++j) { aG[j] = 0.f; aV[j] = 0.f; }
    #pragma unroll 2
    for (int k = 0; k < 128; ++k) {
        float x = S[l*129 + k];                    // bank (l+k)%32: conflict-free
        const float* wr = Wbig + k*256;
        #pragma unroll
        for (int j = 0; j < 16; ++j) aS[j] = fmaf(x, wr[sc0u + j], aS[j]);
        const float4* gq = (const float4*)(wr + 128) + widv*2;
        const float4* vq = (const float4*)(wr + 192) + widv*2;
        float4 g0 = gq[0], g1 = gq[1];
        float4 v0 = vq[0], v1 = vq[1];
        FMA4(aG + 0, x, g0);
        FMA4(aG + 4, x, g1);
        FMA4(aV + 0, x, v0);
        FMA4(aV + 4, x, v1);
    }
    // fold x2s; the vec phase accumulates S2 directly into aS/aG
    const float x2s = x2r.x;
    #pragma unroll
    for (int j = 0; j < 16; ++j) aS[j] *= x2s;
    #pragma unroll
    for (int j = 0; j < 8; ++j)  aG[j] *= x2s;
    __syncthreads();                               // all x1s reads done

    // ---- write fea_w tile into S (scalar writes, pitch 129)
    #pragma unroll
    for (int r = 0; r < 4; ++r) {
        int f = t + r*512;
        int ee = f >> 5, c4 = f & 31;
        float* d = &S[ee*129 + c4*4];
        d[0] = fwst[r].x; d[1] = fwst[r].y; d[2] = fwst[r].z; d[3] = fwst[r].w;
    }
    __syncthreads();

    // ---------------- FC layer 0: h0 = silu(fw @ w0 + b0); 8 cols, K=128
    // cols 0..3 via SMEM, cols 4..7 via VMEM
    float ha[8];
    #pragma unroll
    for (int j = 0; j < 8; ++j) ha[j] = fc_b0[wv0u + j];
    #pragma unroll 2
    for (int k = 0; k < 128; ++k) {
        float x = S[l*129 + k];
        const float* wr = fc_w0 + k*64;
        #pragma unroll
        for (int j = 0; j < 4; ++j) ha[j] = fmaf(x, wr[wv0u + j], ha[j]);
        float4 w4 = ((const float4*)wr)[widv*2 + 1];
        FMA4(ha + 4, x, w4);
    }
    #pragma unroll
    for (int j = 0; j < 8; ++j) {
        float z = ha[j];
        H[(wv0u + j)*64 + l] = z * sigmoidf_(z);
    }
    __syncthreads();                               // h0 ready; fw reads done

    // ---------------- FC layer 1: h1 = silu(h0 @ w1 + b1); 8 cols, K=64
    #pragma unroll
    for (int j = 0; j < 8; ++j) ha[j] = fc_b1[wv0u + j];
    #pragma unroll 2
    for (int k = 0; k < 64; ++k) {
        float x = H[k*64 + l];                     // bank l%32: 2-way, free
        const float* wr = fc_w1 + k*64;
        #pragma unroll
        for (int j = 0; j < 4; ++j) ha[j] = fmaf(x, wr[wv0u + j], ha[j]);
        float4 w4 = ((const float4*)wr)[widv*2 + 1];
        FMA4(ha + 4, x, w4);
    }
    #pragma unroll
    for (int j = 0; j < 8; ++j) {
        float z = ha[j];
        S[(wv0u + j)*64 + l] = z * sigmoidf_(z);   // h1 into S head (fw dead)
    }
    __syncthreads();                               // h1 ready

    // ---------------- FC layer 2: W = h1 @ w2 + b2; 16 scal + 8 gate cols, K=64
    // scal via SMEM (dwordx16), gate via VMEM (2 dwordx4)
    float aWs[16], aWg[8];
    #pragma unroll
    for (int j = 0; j < 16; ++j) aWs[j] = fc_b2[sc0u + j];
    #pragma unroll
    for (int j = 0; j < 8; ++j)  aWg[j] = fc_b2[128 + wv0u + j];
    #pragma unroll 2
    for (int k = 0; k < 64; ++k) {
        float x = S[k*64 + l];
        const float* wr = fc_w2 + k*192;
        #pragma unroll
        for (int j = 0; j < 16; ++j) aWs[j] = fmaf(x, wr[sc0u + j], aWs[j]);
        const float4* gq = (const float4*)(wr + 128) + widv*2;
        float4 g0 = gq[0], g1 = gq[1];
        FMA4(aWg + 0, x, g0);
        FMA4(aWg + 4, x, g1);
    }

    // ---- stage x1v tile: loads issued before the barrier, LDS writes after
    float4 xvst[6];
    #pragma unroll
    for (int r = 0; r < 6; ++r) {
        int f = t + r*512;                // 3072 float4 = 64x192
        int ee = f / 48, c4 = f - ee*48;
        xvst[r] = *(const float4*)(fea_in1 + (e0b + ee)*320 + 128 + c4*4);
    }
    __syncthreads();                               // h1 reads done
    #pragma unroll
    for (int r = 0; r < 6; ++r) {
        int f = t + r*512;
        int ee = f / 48, c4 = f - ee*48;
        float* d = &lds[ee*193 + c4*4];            // [64][193], scalar writes
        d[0] = xvst[r].x; d[1] = xvst[r].y; d[2] = xvst[r].z; d[3] = xvst[r].w;
    }
    __syncthreads();

    // ---------------- vec branch: A3 (8w x 3i) + S2 accumulated into aS/aG, K=64
    // Wd-scal via SMEM (dwordx16), Wd-gate + Wp3 via VMEM (4 dwordx4 / u)
    const float c1 = x2r.y, c2 = x2r.z, c3 = x2r.w;
    float aA3[8][3];
    #pragma unroll
    for (int j = 0; j < 8; ++j) { aA3[j][0]=0.f; aA3[j][1]=0.f; aA3[j][2]=0.f; }
    #pragma unroll 2
    for (int u = 0; u < 64; ++u) {
        float v0 = lds[l*193 + u*3 + 0];           // bank (l+3u+i)%32: conflict-free
        float v1 = lds[l*193 + u*3 + 1];
        float v2 = lds[l*193 + u*3 + 2];
        const float4* wp = (const float4*)(Wp3 + u*64) + widv*2;
        float4 p0 = wp[0], p1 = wp[1];
        #pragma unroll
        for (int i4 = 0; i4 < 4; ++i4) {
            const float w0 = (&p0.x)[i4];
            const float w1 = (&p1.x)[i4];
            aA3[i4][0]   = fmaf(v0, w0, aA3[i4][0]);
            aA3[i4][1]   = fmaf(v1, w0, aA3[i4][1]);
            aA3[i4][2]   = fmaf(v2, w0, aA3[i4][2]);
            aA3[4+i4][0] = fmaf(v0, w1, aA3[4+i4][0]);
            aA3[4+i4][1] = fmaf(v1, w1, aA3[4+i4][1]);
            aA3[4+i4][2] = fmaf(v2, w1, aA3[4+i4][2]);
        }
        const float du = fmaf(v0, c1, fmaf(v1, c2, v2*c3));
        const float* wd = Wd + u*192;
        #pragma unroll
        for (int j = 0; j < 16; ++j) aS[j] = fmaf(du, wd[sc0u + j], aS[j]);
        const float4* gq = (const float4*)(wd + 128) + widv*2;
        float4 g0 = gq[0], g1 = gq[1];
        FMA4(aG + 0, du, g0);
        FMA4(aG + 4, du, g1);
    }

    // ---------------- epilogue: all in registers, direct stores
    float* orow = out + e*320;
    #pragma unroll
    for (int q = 0; q < 4; ++q) {
        float o[4];
        #pragma unroll
        for (int r = 0; r < 4; ++r) {
            const int j = q*4 + r;
            float s = aS[j];                       // = S1*x2s + S2
            o[r] = s * sigmoidf_(s) * aWs[j];
        }
        *(float4*)(orow + sc0u + q*4) = make_float4(o[0], o[1], o[2], o[3]);
    }
    float x2v[3] = {c1, c2, c3};
    float vo[24];
    #pragma unroll
    for (int j = 0; j < 8; ++j) {
        float g  = aG[j];                          // = G1*x2s + G2
        float sg = sigmoidf_(g) * aWg[j];
        #pragma unroll
        for (int i = 0; i < 3; ++i)
            vo[j*3 + i] = sg * fmaf(aV[j], x2v[i], aA3[j][i] * x2s);
    }
    #pragma unroll
    for (int q = 0; q < 6; ++q)
        *(float4*)(orow + 128 + wv0u*3 + q*4) =
            make_float4(vo[q*4], vo[q*4+1], vo[q*4+2], vo[q*4+3]);
}

// ---------------------------------------------------------------- launch
extern "C" void kernel_launch(void* const* d_in, const int* in_sizes, int n_in,
                              void* d_out, int out_size, void* d_ws, size_t ws_size,
                              hipStream_t stream) {
    const float* fea_in1 = (const float*)d_in[0];
    const float* fea_in2 = (const float*)d_in[1];
    const float* fea_w   = (const float*)d_in[2];
    // d_in[3] = batch_edge (unused by reference)
    const float* w1_p0 = (const float*)d_in[4];
    const float* w2_p0 = (const float*)d_in[5];
    const float* w1_p1 = (const float*)d_in[6];
    const float* w2_p1 = (const float*)d_in[7];
    const float* w1_p2 = (const float*)d_in[8];
    const float* w2_p2 = (const float*)d_in[9];
    const float* w1_p3 = (const float*)d_in[10];
    const float* w2_p3 = (const float*)d_in[11];
    const float* w1_p4 = (const float*)d_in[12];
    const float* w2_p4 = (const float*)d_in[13];
    const float* w1_p5 = (const float*)d_in[14];
    const float* w2_p5 = (const float*)d_in[15];
    const float* fc_w0 = (const float*)d_in[16];
    const float* fc_b0 = (const float*)d_in[17];
    const float* fc_w1 = (const float*)d_in[18];
    const float* fc_b1 = (const float*)d_in[19];
    const float* fc_w2 = (const float*)d_in[20];
    const float* fc_b2 = (const float*)d_in[21];

    const int E = in_sizes[0] / 320;   // 200000

    float* ws   = (float*)d_ws;
    float* Wbig = ws;                  // 32768 floats
    float* Wd   = ws + 32768;          // 12288 floats
    float* Wp3  = ws + 45056;          // 4096 floats
    float* out  = (float*)d_out;

    prep_weights<<<192, 256, 0, stream>>>(w1_p0, w2_p0, w1_p1, w2_p1, w1_p2, w2_p2,
                                          w1_p3, w2_p3, w1_p4, w2_p4, w1_p5, w2_p5,
                                          Wbig, Wd, Wp3);
    fused_kernel<<<E/64, 512, 0, stream>>>(fea_in1, fea_in2, fea_w,
                                           fc_w0, fc_b0, fc_w1, fc_b1, fc_w2, fc_b2,
                                           Wbig, Wd, Wp3, out);
}

// Round 5
// 1046.290 us; speedup vs baseline: 2.3287x; 1.2634x over previous
//
#include <hip/hip_runtime.h>

// EquiConv fully-fused pipeline (round 6): MFMA split-bf16 rewrite.
// E = 200000, MUL_S = 128, MUL_V = 64, FC_IN = 128, FC_HID = 64, LEN_W = 192.
//
// All six matmuls (S1, FC0, FC1, FC2, A3, S2) run on the matrix cores with
// 16x16x32 bf16 MFMA. fp32 precision is recovered by a 2-term bf16 split
// (hi+lo ~ 18-bit mantissa): A*B = Ah*Bh + Al*Bh + Ah*Bl, implemented as
// three K-passes of one GEMM. A-tiles live in LDS as [Ah|Al] rows (odd-16B
// pitch -> conflict-free ds_read_b128 fragments); weights are prep-split
// into [Bh|Bl] and stored FRAGMENT-ORDERED so each B fragment load is one
// fully-coalesced 1KB wave read (16B/lane).
//
// Geometry: block = 512 thr = 8 waves = 64 edges. Wave (cw = wv&3, rw = wv>>2)
// owns row-tiles {2rw, 2rw+1} (16 edges each) and a fixed SEMANTIC column set:
//   scal cols  [32cw,32cw+32)   (tiles 2cw, 2cw+1)
//   gate/vcoef w-range [16cw,16cw+16)
//   vec-out n = 3w+i range [48cw, 48cw+48) (tiles 3cw..3cw+2)
// so S1/S2/Wout/A3 fragments align per-lane and the epilogue is register-local;
// the w = n/3 remap for gate/vcoef is two ds_bpermutes (within-wave).
// A3 expanded: A3[e][3w+i] = xv_flat[e][:] @ Wp3' where
// Wp3'[3w+i][3u+ii] = (i==ii) * Wp3[u][w]  (prep-built, K=192).
// S2 accumulates directly into the x2s-folded S1 accumulators (same C-space).
//
// MFMA layouts used (gfx950, guide-verified):
//   A-frag: lane holds A[row = l&15][k = 8*(l>>4) + 0..7]   (8 contig bf16)
//   B-frag: lane holds B[k = 8*(l>>4) + 0..7][col = l&15]   (from B^T storage)
//   C/D  : col = l&15, row = 4*(l>>4) + reg
//
// ws (u16 elems): WB 0 (65536) | W0 65536 (16384) | W1 81920 (8192)
//                 W2 90112 (24576) | WP 114688 (73728) | WD 188416 (24576)

typedef short bf16x8 __attribute__((ext_vector_type(8)));
typedef float f32x4 __attribute__((ext_vector_type(4)));
typedef unsigned short u16;
typedef unsigned short u16x4 __attribute__((ext_vector_type(4)));

#define MFMA16(a, b, c) __builtin_amdgcn_mfma_f32_16x16x32_bf16((a), (b), (c), 0, 0, 0)

__device__ __forceinline__ u16 f2bf(float x) {
    unsigned u = __float_as_uint(x);
    u += 0x7FFFu + ((u >> 16) & 1u);
    return (u16)(u >> 16);
}
__device__ __forceinline__ float bf2f(u16 h) {
    return __uint_as_float(((unsigned)h) << 16);
}
__device__ __forceinline__ float sigmoidf_(float x) { return 1.0f / (1.0f + __expf(-x)); }

__device__ __forceinline__ void split_wr(u16* hip, u16* lop, float4 v) {
    u16x4 h, lo;
    h.x = f2bf(v.x); h.y = f2bf(v.y); h.z = f2bf(v.z); h.w = f2bf(v.w);
    lo.x = f2bf(v.x - bf2f(h.x)); lo.y = f2bf(v.y - bf2f(h.y));
    lo.z = f2bf(v.z - bf2f(h.z)); lo.w = f2bf(v.w - bf2f(h.w));
    *(u16x4*)hip = h;
    *(u16x4*)lop = lo;
}

// ---------------------------------------------------------------- prep
// Builds all split-bf16, fragment-ordered weight matrices. One thread per
// output u16. Element gid -> (region, nt, kb, lane, j):
//   flat = ((nt*KB2 + kb)*64 + lane)*8 + j ; value = W[k][n] pre-scaled,
//   n = 16*nt + (lane&15), k = 32*(kb mod KS) + 8*(lane>>4) + j,
//   kb < KS -> hi part, else lo part.   (KB2 = K/16, KS = K/32)
__global__ __launch_bounds__(256) void prep_weights(
    const float* __restrict__ w1_p0, const float* __restrict__ w2_p0,
    const float* __restrict__ w1_p1, const float* __restrict__ w2_p1,
    const float* __restrict__ w1_p2, const float* __restrict__ w2_p2,
    const float* __restrict__ w1_p3, const float* __restrict__ w2_p3,
    const float* __restrict__ w1_p4, const float* __restrict__ w2_p4,
    const float* __restrict__ w1_p5, const float* __restrict__ w2_p5,
    const float* __restrict__ fc_w0, const float* __restrict__ fc_w1,
    const float* __restrict__ fc_w2,
    u16* __restrict__ W)
{
    const float INV_S = 0.08838834764831845f;   // 1/sqrt(128)
    const float INV_V = 0.125f;                 // 1/sqrt(64)
    const float SQ2   = 0.7071067811865476f;
    const float SQ3   = 0.5773502691896258f;
    int gid = blockIdx.x * 256 + threadIdx.x;
    if (gid >= 212992) return;
    float w = 0.f;
    int islo = 0;
    if (gid < 65536) {                       // WB: N=256 K=128 (Wbig)
        int g = gid, j = g & 7, ll = (g >> 3) & 63, rest = g >> 9;
        int kb = rest & 7, nt = rest >> 3;
        int n = nt * 16 + (ll & 15);
        islo = (kb >= 4);
        int k = 32 * (kb & 3) + 8 * (ll >> 4) + j;
        if (n < 128)      w = w1_p0[k * 128 + n] * w2_p0[n];
        else if (n < 192) w = w1_p1[k * 64 + (n - 128)] * w2_p1[n - 128];
        else              w = w1_p2[k * 64 + (n - 192)] * w2_p2[n - 192];
        w *= (INV_S * SQ2);
    } else if (gid < 81920) {                // W0: N=64 K=128
        int g = gid - 65536, j = g & 7, ll = (g >> 3) & 63, rest = g >> 9;
        int kb = rest & 7, nt = rest >> 3;
        int n = nt * 16 + (ll & 15);
        islo = (kb >= 4);
        int k = 32 * (kb & 3) + 8 * (ll >> 4) + j;
        w = fc_w0[k * 64 + n];
    } else if (gid < 90112) {                // W1: N=64 K=64
        int g = gid - 81920, j = g & 7, ll = (g >> 3) & 63, rest = g >> 9;
        int kb = rest & 3, nt = rest >> 2;
        int n = nt * 16 + (ll & 15);
        islo = (kb >= 2);
        int k = 32 * (kb & 1) + 8 * (ll >> 4) + j;
        w = fc_w1[k * 64 + n];
    } else if (gid < 114688) {               // W2: N=192 K=64
        int g = gid - 90112, j = g & 7, ll = (g >> 3) & 63, rest = g >> 9;
        int kb = rest & 3, nt = rest >> 2;
        int n = nt * 16 + (ll & 15);
        islo = (kb >= 2);
        int k = 32 * (kb & 1) + 8 * (ll >> 4) + j;
        w = fc_w2[k * 192 + n];
    } else if (gid < 188416) {               // WP: N=192 K=192 (Wp3 expanded)
        int g = gid - 114688, j = g & 7, ll = (g >> 3) & 63, rest = g >> 9;
        int kb = rest % 12, nt = rest / 12;
        int n = nt * 16 + (ll & 15);
        islo = (kb >= 6);
        int k = 32 * (islo ? kb - 6 : kb) + 8 * (ll >> 4) + j;
        int u = k / 3, ii = k - 3 * u;
        int wq = n / 3, i = n - 3 * wq;
        w = (i == ii) ? w1_p3[u * 64 + wq] * w2_p3[wq] * (INV_V * SQ2) : 0.f;
    } else {                                 // WD: N=192 K=64 (Wd)
        int g = gid - 188416, j = g & 7, ll = (g >> 3) & 63, rest = g >> 9;
        int kb = rest & 3, nt = rest >> 2;
        int n = nt * 16 + (ll & 15);
        islo = (kb >= 2);
        int k = 32 * (kb & 1) + 8 * (ll >> 4) + j;
        w = (n < 128 ? w1_p4[k * 128 + n] * w2_p4[n]
                     : w1_p5[k * 64 + (n - 128)] * w2_p5[n - 128]) * (INV_V * SQ3 * SQ2);
    }
    u16 h = f2bf(w);
    W[gid] = islo ? f2bf(w - bf2f(h)) : h;
}

// ---------------------------------------------------------------- fused
__global__ __launch_bounds__(512, 4) void fused_kernel(
    const float* __restrict__ fea_in1, const float* __restrict__ fea_in2,
    const float* __restrict__ fea_w,
    const float* __restrict__ fc_b0, const float* __restrict__ fc_b1,
    const float* __restrict__ fc_b2,
    const u16* __restrict__ Wg,
    float* __restrict__ out)
{
    // LDS: B1 50176B (A' staging: x1s/fw pitch 264, xv pitch 392)
    //      B2 17408B (h0'/h1'/d' pitch 136) | X2 1088B ([4][68] f32)
    __shared__ __align__(16) u16 SM[34336];
    u16* B1 = SM;
    u16* B2 = SM + 25088;
    float* X2 = (float*)(SM + 33792);

    const int t  = threadIdx.x;
    const int l  = t & 63;
    const int wv = t >> 6;
    const int cw = wv & 3;
    const int rw = wv >> 2;
    const int lm = l & 15;
    const int lk = l >> 4;
    const int lk8 = lk * 8;
    const long e0b = (long)blockIdx.x * 64;

    // ---- stage x2 transposed [j][e]
    if (t < 64) {
        float4 v = *(const float4*)(fea_in2 + (e0b + t) * 4);
        X2[t] = v.x; X2[68 + t] = v.y; X2[136 + t] = v.z; X2[204 + t] = v.w;
    }
    // ---- stage A'_s1 = split(x1s): rows [Ah(128)|Al(128)], pitch 264
    #pragma unroll
    for (int r = 0; r < 4; ++r) {
        int f = t + r * 512, ee = f >> 5, c4 = f & 31;
        float4 v = *(const float4*)(fea_in1 + (e0b + ee) * 320 + c4 * 4);
        split_wr(&B1[ee * 264 + c4 * 4], &B1[ee * 264 + 128 + c4 * 4], v);
    }
    // ---- prefetch fea_w tile into regs (written to B1 after S1)
    float4 fwst[4];
    #pragma unroll
    for (int r = 0; r < 4; ++r) {
        int f = t + r * 512, ee = f >> 5, c4 = f & 31;
        fwst[r] = *(const float4*)(fea_w + (e0b + ee) * 128 + c4 * 4);
    }
    __syncthreads();

    // ================ S1: [64x128] @ Wbig -> scal(2 tiles) gate(1) vcoef(1)
    f32x4 aS1[4][2] = {};
    {
        const int ctn[4] = {2 * cw, 2 * cw + 1, 8 + cw, 12 + cw};
        const u16* bp[4];
        #pragma unroll
        for (int c = 0; c < 4; ++c) bp[c] = Wg + (ctn[c] * 8) * 512 + l * 8;
        const u16* a0p = B1 + (16 * (2 * rw + 0) + lm) * 264 + lk8;
        const u16* a1p = B1 + (16 * (2 * rw + 1) + lm) * 264 + lk8;
        #pragma unroll
        for (int pass = 0; pass < 3; ++pass) {
            const int ao  = (pass == 1) ? 128 : 0;
            const int kb0 = (pass == 2) ? 4 : 0;
            #pragma unroll
            for (int ks = 0; ks < 4; ++ks) {
                bf16x8 a0 = *(const bf16x8*)(a0p + ao + 32 * ks);
                bf16x8 a1 = *(const bf16x8*)(a1p + ao + 32 * ks);
                #pragma unroll
                for (int c = 0; c < 4; ++c) {
                    bf16x8 b = *(const bf16x8*)(bp[c] + (kb0 + ks) * 512);
                    aS1[c][0] = MFMA16(a0, b, aS1[c][0]);
                    aS1[c][1] = MFMA16(a1, b, aS1[c][1]);
                }
            }
        }
    }
    // fold x2s into scal+gate (NOT vcoef); keep x2s for the epilogue
    float x2s[2][4];
    #pragma unroll
    for (int m = 0; m < 2; ++m)
        #pragma unroll
        for (int r = 0; r < 4; ++r) {
            x2s[m][r] = X2[16 * (2 * rw + m) + 4 * lk + r];
            aS1[0][m][r] *= x2s[m][r];
            aS1[1][m][r] *= x2s[m][r];
            aS1[2][m][r] *= x2s[m][r];
        }
    __syncthreads();                         // S1 reads of B1 done

    // ---- write A'_fw over B1; prefetch x1v
    #pragma unroll
    for (int r = 0; r < 4; ++r) {
        int f = t + r * 512, ee = f >> 5, c4 = f & 31;
        split_wr(&B1[ee * 264 + c4 * 4], &B1[ee * 264 + 128 + c4 * 4], fwst[r]);
    }
    float4 xvst[6];
    #pragma unroll
    for (int r = 0; r < 6; ++r) {
        int f = t + r * 512, ee = f / 48, c4 = f - ee * 48;
        xvst[r] = *(const float4*)(fea_in1 + (e0b + ee) * 320 + 128 + c4 * 4);
    }
    __syncthreads();

    // ================ FC0: [64x128] @ w0 -> 1 col-tile
    f32x4 aF[2] = {};
    {
        const u16* bp = Wg + 65536 + (cw * 8) * 512 + l * 8;
        const u16* a0p = B1 + (16 * (2 * rw + 0) + lm) * 264 + lk8;
        const u16* a1p = B1 + (16 * (2 * rw + 1) + lm) * 264 + lk8;
        #pragma unroll
        for (int pass = 0; pass < 3; ++pass) {
            const int ao  = (pass == 1) ? 128 : 0;
            const int kb0 = (pass == 2) ? 4 : 0;
            #pragma unroll
            for (int ks = 0; ks < 4; ++ks) {
                bf16x8 a0 = *(const bf16x8*)(a0p + ao + 32 * ks);
                bf16x8 a1 = *(const bf16x8*)(a1p + ao + 32 * ks);
                bf16x8 b = *(const bf16x8*)(bp + (kb0 + ks) * 512);
                aF[0] = MFMA16(a0, b, aF[0]);
                aF[1] = MFMA16(a1, b, aF[1]);
            }
        }
    }
    {   // h0 = silu(aF + b0) -> B2 split rows [Hh(64)|Hl(64)], pitch 136
        float bb = fc_b0[16 * cw + lm];
        #pragma unroll
        for (int m = 0; m < 2; ++m)
            #pragma unroll
            for (int r = 0; r < 4; ++r) {
                float z = aF[m][r] + bb;
                float s = z * sigmoidf_(z);
                int e = 16 * (2 * rw + m) + 4 * lk + r;
                int kc = 16 * cw + lm;
                u16 hh = f2bf(s);
                B2[e * 136 + kc] = hh;
                B2[e * 136 + 64 + kc] = f2bf(s - bf2f(hh));
            }
    }
    __syncthreads();                         // h0 ready; all fw reads done

    // ================ FC1: [64x64] @ w1
    f32x4 aH[2] = {};
    {
        const u16* bp = Wg + 81920 + (cw * 4) * 512 + l * 8;
        const u16* a0p = B2 + (16 * (2 * rw + 0) + lm) * 136 + lk8;
        const u16* a1p = B2 + (16 * (2 * rw + 1) + lm) * 136 + lk8;
        #pragma unroll
        for (int pass = 0; pass < 3; ++pass) {
            const int ao  = (pass == 1) ? 64 : 0;
            const int kb0 = (pass == 2) ? 2 : 0;
            #pragma unroll
            for (int ks = 0; ks < 2; ++ks) {
                bf16x8 a0 = *(const bf16x8*)(a0p + ao + 32 * ks);
                bf16x8 a1 = *(const bf16x8*)(a1p + ao + 32 * ks);
                bf16x8 b = *(const bf16x8*)(bp + (kb0 + ks) * 512);
                aH[0] = MFMA16(a0, b, aH[0]);
                aH[1] = MFMA16(a1, b, aH[1]);
            }
        }
    }
    // write A'_xv into B1 (fw dead since the last barrier): pitch 392
    #pragma unroll
    for (int r = 0; r < 6; ++r) {
        int f = t + r * 512, ee = f / 48, c4 = f - ee * 48, cc = 4 * c4;
        split_wr(&B1[ee * 392 + cc], &B1[ee * 392 + 192 + cc], xvst[r]);
    }
    __syncthreads();                         // all h0 reads done; xv staged

    {   // h1 = silu(aH + b1) -> B2 (overwrites h0)
        float bb = fc_b1[16 * cw + lm];
        #pragma unroll
        for (int m = 0; m < 2; ++m)
            #pragma unroll
            for (int r = 0; r < 4; ++r) {
                float z = aH[m][r] + bb;
                float s = z * sigmoidf_(z);
                int e = 16 * (2 * rw + m) + 4 * lk + r;
                int kc = 16 * cw + lm;
                u16 hh = f2bf(s);
                B2[e * 136 + kc] = hh;
                B2[e * 136 + 64 + kc] = f2bf(s - bf2f(hh));
            }
    }
    __syncthreads();                         // h1 ready

    // ================ FC2: [64x64] @ w2 -> Wout (scal 2 tiles + gate 1)
    f32x4 aW[3][2] = {};
    {
        const int ctn[3] = {2 * cw, 2 * cw + 1, 8 + cw};
        const u16* bp[3];
        #pragma unroll
        for (int c = 0; c < 3; ++c) bp[c] = Wg + 90112 + (ctn[c] * 4) * 512 + l * 8;
        const u16* a0p = B2 + (16 * (2 * rw + 0) + lm) * 136 + lk8;
        const u16* a1p = B2 + (16 * (2 * rw + 1) + lm) * 136 + lk8;
        #pragma unroll
        for (int pass = 0; pass < 3; ++pass) {
            const int ao  = (pass == 1) ? 64 : 0;
            const int kb0 = (pass == 2) ? 2 : 0;
            #pragma unroll
            for (int ks = 0; ks < 2; ++ks) {
                bf16x8 a0 = *(const bf16x8*)(a0p + ao + 32 * ks);
                bf16x8 a1 = *(const bf16x8*)(a1p + ao + 32 * ks);
                #pragma unroll
                for (int c = 0; c < 3; ++c) {
                    bf16x8 b = *(const bf16x8*)(bp[c] + (kb0 + ks) * 512);
                    aW[c][0] = MFMA16(a0, b, aW[c][0]);
                    aW[c][1] = MFMA16(a1, b, aW[c][1]);
                }
            }
        }
        float b0v = fc_b2[32 * cw + lm];
        float b1v = fc_b2[32 * cw + 16 + lm];
        float bgv = fc_b2[128 + 16 * cw + lm];
        #pragma unroll
        for (int m = 0; m < 2; ++m)
            #pragma unroll
            for (int r = 0; r < 4; ++r) {
                aW[0][m][r] += b0v;
                aW[1][m][r] += b1v;
                aW[2][m][r] += bgv;
            }
    }
    __syncthreads();                         // h1 reads done

    // ================ d[e][u] = sum_i xv[e][u][i]*x2v[e][i] -> A'_d (B2)
    {
        int de = t & 63, u0 = (t >> 6) * 8;
        float c1 = X2[68 + de], c2 = X2[136 + de], c3 = X2[204 + de];
        #pragma unroll
        for (int q = 0; q < 8; ++q) {
            int u = u0 + q;
            float xa = bf2f(B1[de * 392 + 3 * u + 0]) + bf2f(B1[de * 392 + 192 + 3 * u + 0]);
            float xb = bf2f(B1[de * 392 + 3 * u + 1]) + bf2f(B1[de * 392 + 192 + 3 * u + 1]);
            float xc = bf2f(B1[de * 392 + 3 * u + 2]) + bf2f(B1[de * 392 + 192 + 3 * u + 2]);
            float d = xa * c1 + xb * c2 + xc * c3;
            u16 hh = f2bf(d);
            B2[de * 136 + u] = hh;
            B2[de * 136 + 64 + u] = f2bf(d - bf2f(hh));
        }
    }
    __syncthreads();                         // A'_d ready (xv untouched)

    // ================ A3': [64x192] @ Wp3' -> 3 col-tiles (n = 3w+i space)
    f32x4 aA[3][2] = {};
    {
        const int ctn[3] = {3 * cw, 3 * cw + 1, 3 * cw + 2};
        const u16* bp[3];
        #pragma unroll
        for (int c = 0; c < 3; ++c) bp[c] = Wg + 114688 + (ctn[c] * 12) * 512 + l * 8;
        const u16* a0p = B1 + (16 * (2 * rw + 0) + lm) * 392 + lk8;
        const u16* a1p = B1 + (16 * (2 * rw + 1) + lm) * 392 + lk8;
        #pragma unroll
        for (int pass = 0; pass < 3; ++pass) {
            const int ao  = (pass == 1) ? 192 : 0;
            const int kb0 = (pass == 2) ? 6 : 0;
            #pragma unroll
            for (int ks = 0; ks < 6; ++ks) {
                bf16x8 a0 = *(const bf16x8*)(a0p + ao + 32 * ks);
                bf16x8 a1 = *(const bf16x8*)(a1p + ao + 32 * ks);
                #pragma unroll
                for (int c = 0; c < 3; ++c) {
                    bf16x8 b = *(const bf16x8*)(bp[c] + (kb0 + ks) * 512);
                    aA[c][0] = MFMA16(a0, b, aA[c][0]);
                    aA[c][1] = MFMA16(a1, b, aA[c][1]);
                }
            }
        }
    }

    // ================ S2: [64x64] @ Wd, accumulated INTO aS1[0..2]
    {
        const int ctn[3] = {2 * cw, 2 * cw + 1, 8 + cw};
        const u16* bp[3];
        #pragma unroll
        for (int c = 0; c < 3; ++c) bp[c] = Wg + 188416 + (ctn[c] * 4) * 512 + l * 8;
        const u16* a0p = B2 + (16 * (2 * rw + 0) + lm) * 136 + lk8;
        const u16* a1p = B2 + (16 * (2 * rw + 1) + lm) * 136 + lk8;
        #pragma unroll
        for (int pass = 0; pass < 3; ++pass) {
            const int ao  = (pass == 1) ? 64 : 0;
            const int kb0 = (pass == 2) ? 2 : 0;
            #pragma unroll
            for (int ks = 0; ks < 2; ++ks) {
                bf16x8 a0 = *(const bf16x8*)(a0p + ao + 32 * ks);
                bf16x8 a1 = *(const bf16x8*)(a1p + ao + 32 * ks);
                #pragma unroll
                for (int c = 0; c < 3; ++c) {
                    bf16x8 b = *(const bf16x8*)(bp[c] + (kb0 + ks) * 512);
                    aS1[c][0] = MFMA16(a0, b, aS1[c][0]);
                    aS1[c][1] = MFMA16(a1, b, aS1[c][1]);
                }
            }
        }
    }

    // ================ epilogue (all in C-fragment space)
    // scal: s = S1*x2s + S2 -> silu(s) * Wout
    #pragma unroll
    for (int c2 = 0; c2 < 2; ++c2)
        #pragma unroll
        for (int m = 0; m < 2; ++m)
            #pragma unroll
            for (int r = 0; r < 4; ++r) {
                float s = aS1[c2][m][r];
                float o = s * sigmoidf_(s) * aW[c2][m][r];
                int e = 16 * (2 * rw + m) + 4 * lk + r;
                out[(e0b + e) * 320 + 32 * cw + 16 * c2 + lm] = o;
            }
    // gate combine: G = sigmoid(g)*Wout_gate  (per-lane, w = 16cw + lm)
    float G[2][4];
    #pragma unroll
    for (int m = 0; m < 2; ++m)
        #pragma unroll
        for (int r = 0; r < 4; ++r)
            G[m][r] = sigmoidf_(aS1[2][m][r]) * aW[2][m][r];
    // vec out: o = G[w] * (V[w]*x2v_i + A3[n]*x2s), w = n/3, i = n%3
    #pragma unroll
    for (int nt = 0; nt < 3; ++nt) {
        int n = 16 * (3 * cw + nt) + lm;
        int wq = n / 3;
        int i = n - 3 * wq;
        int sl4 = ((l & 48) | (wq - 16 * cw)) * 4;
        #pragma unroll
        for (int m = 0; m < 2; ++m)
            #pragma unroll
            for (int r = 0; r < 4; ++r) {
                float g  = __int_as_float(__builtin_amdgcn_ds_bpermute(sl4, __float_as_int(G[m][r])));
                float vv = __int_as_float(__builtin_amdgcn_ds_bpermute(sl4, __float_as_int(aS1[3][m][r])));
                int e = 16 * (2 * rw + m) + 4 * lk + r;
                float o = g * (vv * X2[68 * (1 + i) + e] + aA[nt][m][r] * x2s[m][r]);
                out[(e0b + e) * 320 + 128 + n] = o;
            }
    }
}

// ---------------------------------------------------------------- launch
extern "C" void kernel_launch(void* const* d_in, const int* in_sizes, int n_in,
                              void* d_out, int out_size, void* d_ws, size_t ws_size,
                              hipStream_t stream) {
    const float* fea_in1 = (const float*)d_in[0];
    const float* fea_in2 = (const float*)d_in[1];
    const float* fea_w   = (const float*)d_in[2];
    // d_in[3] = batch_edge (unused by reference)
    const float* w1_p0 = (const float*)d_in[4];
    const float* w2_p0 = (const float*)d_in[5];
    const float* w1_p1 = (const float*)d_in[6];
    const float* w2_p1 = (const float*)d_in[7];
    const float* w1_p2 = (const float*)d_in[8];
    const float* w2_p2 = (const float*)d_in[9];
    const float* w1_p3 = (const float*)d_in[10];
    const float* w2_p3 = (const float*)d_in[11];
    const float* w1_p4 = (const float*)d_in[12];
    const float* w2_p4 = (const float*)d_in[13];
    const float* w1_p5 = (const float*)d_in[14];
    const float* w2_p5 = (const float*)d_in[15];
    const float* fc_w0 = (const float*)d_in[16];
    const float* fc_b0 = (const float*)d_in[17];
    const float* fc_w1 = (const float*)d_in[18];
    const float* fc_b1 = (const float*)d_in[19];
    const float* fc_w2 = (const float*)d_in[20];
    const float* fc_b2 = (const float*)d_in[21];

    const int E = in_sizes[0] / 320;   // 200000

    u16* W = (u16*)d_ws;               // 212992 u16 = 416 KB
    float* out = (float*)d_out;

    prep_weights<<<832, 256, 0, stream>>>(w1_p0, w2_p0, w1_p1, w2_p1, w1_p2, w2_p2,
                                          w1_p3, w2_p3, w1_p4, w2_p4, w1_p5, w2_p5,
                                          fc_w0, fc_w1, fc_w2, W);
    fused_kernel<<<E / 64, 512, 0, stream>>>(fea_in1, fea_in2, fea_w,
                                             fc_b0, fc_b1, fc_b2, W, out);
}

// Round 6
// 711.512 us; speedup vs baseline: 3.4243x; 1.4705x over previous
//
#include <hip/hip_runtime.h>

// EquiConv fully-fused pipeline (round 7): MFMA split-bf16, spill-free.
// E = 200000, MUL_S = 128, MUL_V = 64, FC_IN = 128, FC_HID = 64, LEN_W = 192.
//
// Same structure as round 6 (all six matmuls on 16x16x32 bf16 MFMA, 2-term
// bf16 split = 3 K-passes, fragment-ordered weights, register-local epilogue).
// Round 6 spilled: launch_bounds(512,4) caps 128 regs/thread and the kernel
// held ~170 (80 acc + 40 prefetch + 8 x2s + hoisted B-loads) -> 1.4 GB of
// scratch writes (WRITE_SIZE 1.64 GB vs 256 MB output). This round cuts
// register pressure to fit the cap with NO structural change:
//   - fea_w / x1v staged directly at the staging point (no reg prefetch, -40)
//   - x2s re-read from the X2 LDS table at fold + epilogue (-8)
//   - 3-pass loops rolled (#pragma unroll 1) to bound hoisted B-loads
//   - d-phase LDS access vectorized (b128) -- fewer instrs + conflicts
//
// MFMA layouts (gfx950, guide-verified):
//   A-frag: lane holds A[row = l&15][k = 8*(l>>4) + 0..7]
//   B-frag: lane holds B[k = 8*(l>>4) + 0..7][col = l&15]
//   C/D  : col = l&15, row = 4*(l>>4) + reg
//
// ws (u16 elems): WB 0 (65536) | W0 65536 (16384) | W1 81920 (8192)
//                 W2 90112 (24576) | WP 114688 (73728) | WD 188416 (24576)

typedef short bf16x8 __attribute__((ext_vector_type(8)));
typedef float f32x4 __attribute__((ext_vector_type(4)));
typedef unsigned short u16;
typedef unsigned short u16x4 __attribute__((ext_vector_type(4)));

#define MFMA16(a, b, c) __builtin_amdgcn_mfma_f32_16x16x32_bf16((a), (b), (c), 0, 0, 0)

__device__ __forceinline__ u16 f2bf(float x) {
    unsigned u = __float_as_uint(x);
    u += 0x7FFFu + ((u >> 16) & 1u);
    return (u16)(u >> 16);
}
__device__ __forceinline__ float bf2f(u16 h) {
    return __uint_as_float(((unsigned)h) << 16);
}
__device__ __forceinline__ float sigmoidf_(float x) { return 1.0f / (1.0f + __expf(-x)); }

__device__ __forceinline__ void split_wr(u16* hip, u16* lop, float4 v) {
    u16x4 h, lo;
    h.x = f2bf(v.x); h.y = f2bf(v.y); h.z = f2bf(v.z); h.w = f2bf(v.w);
    lo.x = f2bf(v.x - bf2f(h.x)); lo.y = f2bf(v.y - bf2f(h.y));
    lo.z = f2bf(v.z - bf2f(h.z)); lo.w = f2bf(v.w - bf2f(h.w));
    *(u16x4*)hip = h;
    *(u16x4*)lop = lo;
}

// ---------------------------------------------------------------- prep
// Builds all split-bf16, fragment-ordered weight matrices. One thread per
// output u16. Element gid -> (region, nt, kb, lane, j):
//   flat = ((nt*KB2 + kb)*64 + lane)*8 + j ; value = W[k][n] pre-scaled,
//   n = 16*nt + (lane&15), k = 32*(kb mod KS) + 8*(lane>>4) + j,
//   kb < KS -> hi part, else lo part.   (KB2 = K/16, KS = K/32)
__global__ __launch_bounds__(256) void prep_weights(
    const float* __restrict__ w1_p0, const float* __restrict__ w2_p0,
    const float* __restrict__ w1_p1, const float* __restrict__ w2_p1,
    const float* __restrict__ w1_p2, const float* __restrict__ w2_p2,
    const float* __restrict__ w1_p3, const float* __restrict__ w2_p3,
    const float* __restrict__ w1_p4, const float* __restrict__ w2_p4,
    const float* __restrict__ w1_p5, const float* __restrict__ w2_p5,
    const float* __restrict__ fc_w0, const float* __restrict__ fc_w1,
    const float* __restrict__ fc_w2,
    u16* __restrict__ W)
{
    const float INV_S = 0.08838834764831845f;   // 1/sqrt(128)
    const float INV_V = 0.125f;                 // 1/sqrt(64)
    const float SQ2   = 0.7071067811865476f;
    const float SQ3   = 0.5773502691896258f;
    int gid = blockIdx.x * 256 + threadIdx.x;
    if (gid >= 212992) return;
    float w = 0.f;
    int islo = 0;
    if (gid < 65536) {                       // WB: N=256 K=128 (Wbig)
        int g = gid, j = g & 7, ll = (g >> 3) & 63, rest = g >> 9;
        int kb = rest & 7, nt = rest >> 3;
        int n = nt * 16 + (ll & 15);
        islo = (kb >= 4);
        int k = 32 * (kb & 3) + 8 * (ll >> 4) + j;
        if (n < 128)      w = w1_p0[k * 128 + n] * w2_p0[n];
        else if (n < 192) w = w1_p1[k * 64 + (n - 128)] * w2_p1[n - 128];
        else              w = w1_p2[k * 64 + (n - 192)] * w2_p2[n - 192];
        w *= (INV_S * SQ2);
    } else if (gid < 81920) {                // W0: N=64 K=128
        int g = gid - 65536, j = g & 7, ll = (g >> 3) & 63, rest = g >> 9;
        int kb = rest & 7, nt = rest >> 3;
        int n = nt * 16 + (ll & 15);
        islo = (kb >= 4);
        int k = 32 * (kb & 3) + 8 * (ll >> 4) + j;
        w = fc_w0[k * 64 + n];
    } else if (gid < 90112) {                // W1: N=64 K=64
        int g = gid - 81920, j = g & 7, ll = (g >> 3) & 63, rest = g >> 9;
        int kb = rest & 3, nt = rest >> 2;
        int n = nt * 16 + (ll & 15);
        islo = (kb >= 2);
        int k = 32 * (kb & 1) + 8 * (ll >> 4) + j;
        w = fc_w1[k * 64 + n];
    } else if (gid < 114688) {               // W2: N=192 K=64
        int g = gid - 90112, j = g & 7, ll = (g >> 3) & 63, rest = g >> 9;
        int kb = rest & 3, nt = rest >> 2;
        int n = nt * 16 + (ll & 15);
        islo = (kb >= 2);
        int k = 32 * (kb & 1) + 8 * (ll >> 4) + j;
        w = fc_w2[k * 192 + n];
    } else if (gid < 188416) {               // WP: N=192 K=192 (Wp3 expanded)
        int g = gid - 114688, j = g & 7, ll = (g >> 3) & 63, rest = g >> 9;
        int kb = rest % 12, nt = rest / 12;
        int n = nt * 16 + (ll & 15);
        islo = (kb >= 6);
        int k = 32 * (islo ? kb - 6 : kb) + 8 * (ll >> 4) + j;
        int u = k / 3, ii = k - 3 * u;
        int wq = n / 3, i = n - 3 * wq;
        w = (i == ii) ? w1_p3[u * 64 + wq] * w2_p3[wq] * (INV_V * SQ2) : 0.f;
    } else {                                 // WD: N=192 K=64 (Wd)
        int g = gid - 188416, j = g & 7, ll = (g >> 3) & 63, rest = g >> 9;
        int kb = rest & 3, nt = rest >> 2;
        int n = nt * 16 + (ll & 15);
        islo = (kb >= 2);
        int k = 32 * (kb & 1) + 8 * (ll >> 4) + j;
        w = (n < 128 ? w1_p4[k * 128 + n] * w2_p4[n]
                     : w1_p5[k * 64 + (n - 128)] * w2_p5[n - 128]) * (INV_V * SQ3 * SQ2);
    }
    u16 h = f2bf(w);
    W[gid] = islo ? f2bf(w - bf2f(h)) : h;
}

// ---------------------------------------------------------------- fused
__global__ __launch_bounds__(512, 4) void fused_kernel(
    const float* __restrict__ fea_in1, const float* __restrict__ fea_in2,
    const float* __restrict__ fea_w,
    const float* __restrict__ fc_b0, const float* __restrict__ fc_b1,
    const float* __restrict__ fc_b2,
    const u16* __restrict__ Wg,
    float* __restrict__ out)
{
    // LDS: B1 50176B (A' staging: x1s/fw pitch 264, xv pitch 392)
    //      B2 17408B (h0'/h1'/d' pitch 136) | X2 1088B ([4][68] f32)
    __shared__ __align__(16) u16 SM[34336];
    u16* B1 = SM;
    u16* B2 = SM + 25088;
    float* X2 = (float*)(SM + 33792);

    const int t  = threadIdx.x;
    const int l  = t & 63;
    const int wv = t >> 6;
    const int cw = wv & 3;
    const int rw = wv >> 2;
    const int lm = l & 15;
    const int lk = l >> 4;
    const int lk8 = lk * 8;
    const long e0b = (long)blockIdx.x * 64;

    // ---- stage x2 transposed [j][e]
    if (t < 64) {
        float4 v = *(const float4*)(fea_in2 + (e0b + t) * 4);
        X2[t] = v.x; X2[68 + t] = v.y; X2[136 + t] = v.z; X2[204 + t] = v.w;
    }
    // ---- stage A'_s1 = split(x1s): rows [Ah(128)|Al(128)], pitch 264
    #pragma unroll
    for (int r = 0; r < 4; ++r) {
        int f = t + r * 512, ee = f >> 5, c4 = f & 31;
        float4 v = *(const float4*)(fea_in1 + (e0b + ee) * 320 + c4 * 4);
        split_wr(&B1[ee * 264 + c4 * 4], &B1[ee * 264 + 128 + c4 * 4], v);
    }
    __syncthreads();

    // ================ S1: [64x128] @ Wbig -> scal(2 tiles) gate(1) vcoef(1)
    f32x4 aS1[4][2] = {};
    {
        const int ctn[4] = {2 * cw, 2 * cw + 1, 8 + cw, 12 + cw};
        const u16* bp[4];
        #pragma unroll
        for (int c = 0; c < 4; ++c) bp[c] = Wg + (ctn[c] * 8) * 512 + l * 8;
        const u16* a0p = B1 + (16 * (2 * rw + 0) + lm) * 264 + lk8;
        const u16* a1p = B1 + (16 * (2 * rw + 1) + lm) * 264 + lk8;
        #pragma unroll 1
        for (int pass = 0; pass < 3; ++pass) {
            const int ao  = (pass == 1) ? 128 : 0;
            const int kb0 = (pass == 2) ? 4 : 0;
            #pragma unroll
            for (int ks = 0; ks < 4; ++ks) {
                bf16x8 a0 = *(const bf16x8*)(a0p + ao + 32 * ks);
                bf16x8 a1 = *(const bf16x8*)(a1p + ao + 32 * ks);
                #pragma unroll
                for (int c = 0; c < 4; ++c) {
                    bf16x8 b = *(const bf16x8*)(bp[c] + (kb0 + ks) * 512);
                    aS1[c][0] = MFMA16(a0, b, aS1[c][0]);
                    aS1[c][1] = MFMA16(a1, b, aS1[c][1]);
                }
            }
        }
    }
    // fold x2s into scal+gate (NOT vcoef); x2s re-read from X2 later
    #pragma unroll
    for (int m = 0; m < 2; ++m)
        #pragma unroll
        for (int r = 0; r < 4; ++r) {
            float xs = X2[16 * (2 * rw + m) + 4 * lk + r];
            aS1[0][m][r] *= xs;
            aS1[1][m][r] *= xs;
            aS1[2][m][r] *= xs;
        }
    __syncthreads();                         // S1 reads of B1 done

    // ---- stage A'_fw over B1 (direct load -> split write, no reg hold)
    #pragma unroll
    for (int r = 0; r < 4; ++r) {
        int f = t + r * 512, ee = f >> 5, c4 = f & 31;
        float4 v = *(const float4*)(fea_w + (e0b + ee) * 128 + c4 * 4);
        split_wr(&B1[ee * 264 + c4 * 4], &B1[ee * 264 + 128 + c4 * 4], v);
    }
    __syncthreads();

    // ================ FC0: [64x128] @ w0 -> 1 col-tile
    f32x4 aF[2] = {};
    {
        const u16* bp = Wg + 65536 + (cw * 8) * 512 + l * 8;
        const u16* a0p = B1 + (16 * (2 * rw + 0) + lm) * 264 + lk8;
        const u16* a1p = B1 + (16 * (2 * rw + 1) + lm) * 264 + lk8;
        #pragma unroll 1
        for (int pass = 0; pass < 3; ++pass) {
            const int ao  = (pass == 1) ? 128 : 0;
            const int kb0 = (pass == 2) ? 4 : 0;
            #pragma unroll
            for (int ks = 0; ks < 4; ++ks) {
                bf16x8 a0 = *(const bf16x8*)(a0p + ao + 32 * ks);
                bf16x8 a1 = *(const bf16x8*)(a1p + ao + 32 * ks);
                bf16x8 b = *(const bf16x8*)(bp + (kb0 + ks) * 512);
                aF[0] = MFMA16(a0, b, aF[0]);
                aF[1] = MFMA16(a1, b, aF[1]);
            }
        }
    }
    {   // h0 = silu(aF + b0) -> B2 split rows [Hh(64)|Hl(64)], pitch 136
        float bb = fc_b0[16 * cw + lm];
        #pragma unroll
        for (int m = 0; m < 2; ++m)
            #pragma unroll
            for (int r = 0; r < 4; ++r) {
                float z = aF[m][r] + bb;
                float s = z * sigmoidf_(z);
                int e = 16 * (2 * rw + m) + 4 * lk + r;
                int kc = 16 * cw + lm;
                u16 hh = f2bf(s);
                B2[e * 136 + kc] = hh;
                B2[e * 136 + 64 + kc] = f2bf(s - bf2f(hh));
            }
    }
    __syncthreads();                         // h0 ready; all fw reads done

    // ================ FC1: [64x64] @ w1
    f32x4 aH[2] = {};
    {
        const u16* bp = Wg + 81920 + (cw * 4) * 512 + l * 8;
        const u16* a0p = B2 + (16 * (2 * rw + 0) + lm) * 136 + lk8;
        const u16* a1p = B2 + (16 * (2 * rw + 1) + lm) * 136 + lk8;
        #pragma unroll
        for (int pass = 0; pass < 3; ++pass) {
            const int ao  = (pass == 1) ? 64 : 0;
            const int kb0 = (pass == 2) ? 2 : 0;
            #pragma unroll
            for (int ks = 0; ks < 2; ++ks) {
                bf16x8 a0 = *(const bf16x8*)(a0p + ao + 32 * ks);
                bf16x8 a1 = *(const bf16x8*)(a1p + ao + 32 * ks);
                bf16x8 b = *(const bf16x8*)(bp + (kb0 + ks) * 512);
                aH[0] = MFMA16(a0, b, aH[0]);
                aH[1] = MFMA16(a1, b, aH[1]);
            }
        }
    }
    // write A'_xv into B1 (fw dead): direct load -> split write, pitch 392
    #pragma unroll
    for (int r = 0; r < 6; ++r) {
        int f = t + r * 512, ee = f / 48, c4 = f - ee * 48, cc = 4 * c4;
        float4 v = *(const float4*)(fea_in1 + (e0b + ee) * 320 + 128 + c4 * 4);
        split_wr(&B1[ee * 392 + cc], &B1[ee * 392 + 192 + cc], v);
    }
    __syncthreads();                         // all h0 reads done; xv staged

    {   // h1 = silu(aH + b1) -> B2 (overwrites h0)
        float bb = fc_b1[16 * cw + lm];
        #pragma unroll
        for (int m = 0; m < 2; ++m)
            #pragma unroll
            for (int r = 0; r < 4; ++r) {
                float z = aH[m][r] + bb;
                float s = z * sigmoidf_(z);
                int e = 16 * (2 * rw + m) + 4 * lk + r;
                int kc = 16 * cw + lm;
                u16 hh = f2bf(s);
                B2[e * 136 + kc] = hh;
                B2[e * 136 + 64 + kc] = f2bf(s - bf2f(hh));
            }
    }
    __syncthreads();                         // h1 ready

    // ================ FC2: [64x64] @ w2 -> Wout (scal 2 tiles + gate 1)
    f32x4 aW[3][2] = {};
    {
        const int ctn[3] = {2 * cw, 2 * cw + 1, 8 + cw};
        const u16* bp[3];
        #pragma unroll
        for (int c = 0; c < 3; ++c) bp[c] = Wg + 90112 + (ctn[c] * 4) * 512 + l * 8;
        const u16* a0p = B2 + (16 * (2 * rw + 0) + lm) * 136 + lk8;
        const u16* a1p = B2 + (16 * (2 * rw + 1) + lm) * 136 + lk8;
        #pragma unroll 1
        for (int pass = 0; pass < 3; ++pass) {
            const int ao  = (pass == 1) ? 64 : 0;
            const int kb0 = (pass == 2) ? 2 : 0;
            #pragma unroll
            for (int ks = 0; ks < 2; ++ks) {
                bf16x8 a0 = *(const bf16x8*)(a0p + ao + 32 * ks);
                bf16x8 a1 = *(const bf16x8*)(a1p + ao + 32 * ks);
                #pragma unroll
                for (int c = 0; c < 3; ++c) {
                    bf16x8 b = *(const bf16x8*)(bp[c] + (kb0 + ks) * 512);
                    aW[c][0] = MFMA16(a0, b, aW[c][0]);
                    aW[c][1] = MFMA16(a1, b, aW[c][1]);
                }
            }
        }
        float b0v = fc_b2[32 * cw + lm];
        float b1v = fc_b2[32 * cw + 16 + lm];
        float bgv = fc_b2[128 + 16 * cw + lm];
        #pragma unroll
        for (int m = 0; m < 2; ++m)
            #pragma unroll
            for (int r = 0; r < 4; ++r) {
                aW[0][m][r] += b0v;
                aW[1][m][r] += b1v;
                aW[2][m][r] += bgv;
            }
    }
    __syncthreads();                         // h1 reads done

    // ================ d[e][u] = sum_i xv[e][u][i]*x2v[e][i] -> A'_d (B2)
    {
        int de = t & 63, u0 = (t >> 6) * 8;
        const u16* bb = &B1[de * 392 + 3 * u0];
        u16 hv[24], lv[24];
        *(bf16x8*)&hv[0]  = *(const bf16x8*)(bb + 0);
        *(bf16x8*)&hv[8]  = *(const bf16x8*)(bb + 8);
        *(bf16x8*)&hv[16] = *(const bf16x8*)(bb + 16);
        *(bf16x8*)&lv[0]  = *(const bf16x8*)(bb + 192);
        *(bf16x8*)&lv[8]  = *(const bf16x8*)(bb + 200);
        *(bf16x8*)&lv[16] = *(const bf16x8*)(bb + 208);
        float c1 = X2[68 + de], c2 = X2[136 + de], c3 = X2[204 + de];
        u16 dh[8], dl[8];
        #pragma unroll
        for (int q = 0; q < 8; ++q) {
            float xa = bf2f(hv[3 * q + 0]) + bf2f(lv[3 * q + 0]);
            float xb = bf2f(hv[3 * q + 1]) + bf2f(lv[3 * q + 1]);
            float xc = bf2f(hv[3 * q + 2]) + bf2f(lv[3 * q + 2]);
            float d = xa * c1 + xb * c2 + xc * c3;
            dh[q] = f2bf(d);
            dl[q] = f2bf(d - bf2f(dh[q]));
        }
        *(bf16x8*)&B2[de * 136 + u0]      = *(bf16x8*)&dh[0];
        *(bf16x8*)&B2[de * 136 + 64 + u0] = *(bf16x8*)&dl[0];
    }
    __syncthreads();                         // A'_d ready (xv untouched)

    // ================ A3': [64x192] @ Wp3' -> 3 col-tiles (n = 3w+i space)
    f32x4 aA[3][2] = {};
    {
        const int ctn[3] = {3 * cw, 3 * cw + 1, 3 * cw + 2};
        const u16* bp[3];
        #pragma unroll
        for (int c = 0; c < 3; ++c) bp[c] = Wg + 114688 + (ctn[c] * 12) * 512 + l * 8;
        const u16* a0p = B1 + (16 * (2 * rw + 0) + lm) * 392 + lk8;
        const u16* a1p = B1 + (16 * (2 * rw + 1) + lm) * 392 + lk8;
        #pragma unroll 1
        for (int pass = 0; pass < 3; ++pass) {
            const int ao  = (pass == 1) ? 192 : 0;
            const int kb0 = (pass == 2) ? 6 : 0;
            #pragma unroll
            for (int ks = 0; ks < 6; ++ks) {
                bf16x8 a0 = *(const bf16x8*)(a0p + ao + 32 * ks);
                bf16x8 a1 = *(const bf16x8*)(a1p + ao + 32 * ks);
                #pragma unroll
                for (int c = 0; c < 3; ++c) {
                    bf16x8 b = *(const bf16x8*)(bp[c] + (kb0 + ks) * 512);
                    aA[c][0] = MFMA16(a0, b, aA[c][0]);
                    aA[c][1] = MFMA16(a1, b, aA[c][1]);
                }
            }
        }
    }

    // ================ S2: [64x64] @ Wd, accumulated INTO aS1[0..2]
    {
        const int ctn[3] = {2 * cw, 2 * cw + 1, 8 + cw};
        const u16* bp[3];
        #pragma unroll
        for (int c = 0; c < 3; ++c) bp[c] = Wg + 188416 + (ctn[c] * 4) * 512 + l * 8;
        const u16* a0p = B2 + (16 * (2 * rw + 0) + lm) * 136 + lk8;
        const u16* a1p = B2 + (16 * (2 * rw + 1) + lm) * 136 + lk8;
        #pragma unroll 1
        for (int pass = 0; pass < 3; ++pass) {
            const int ao  = (pass == 1) ? 64 : 0;
            const int kb0 = (pass == 2) ? 2 : 0;
            #pragma unroll
            for (int ks = 0; ks < 2; ++ks) {
                bf16x8 a0 = *(const bf16x8*)(a0p + ao + 32 * ks);
                bf16x8 a1 = *(const bf16x8*)(a1p + ao + 32 * ks);
                #pragma unroll
                for (int c = 0; c < 3; ++c) {
                    bf16x8 b = *(const bf16x8*)(bp[c] + (kb0 + ks) * 512);
                    aS1[c][0] = MFMA16(a0, b, aS1[c][0]);
                    aS1[c][1] = MFMA16(a1, b, aS1[c][1]);
                }
            }
        }
    }

    // ================ epilogue (all in C-fragment space)
    // scal: s = S1*x2s + S2 -> silu(s) * Wout
    #pragma unroll
    for (int c2 = 0; c2 < 2; ++c2)
        #pragma unroll
        for (int m = 0; m < 2; ++m)
            #pragma unroll
            for (int r = 0; r < 4; ++r) {
                float s = aS1[c2][m][r];
                float o = s * sigmoidf_(s) * aW[c2][m][r];
                int e = 16 * (2 * rw + m) + 4 * lk + r;
                out[(e0b + e) * 320 + 32 * cw + 16 * c2 + lm] = o;
            }
    // gate combine: G = sigmoid(g)*Wout_gate  (per-lane, w = 16cw + lm)
    float G[2][4];
    #pragma unroll
    for (int m = 0; m < 2; ++m)
        #pragma unroll
        for (int r = 0; r < 4; ++r)
            G[m][r] = sigmoidf_(aS1[2][m][r]) * aW[2][m][r];
    // vec out: o = G[w] * (V[w]*x2v_i + A3[n]*x2s), w = n/3, i = n%3
    #pragma unroll
    for (int nt = 0; nt < 3; ++nt) {
        int n = 16 * (3 * cw + nt) + lm;
        int wq = n / 3;
        int i = n - 3 * wq;
        int sl4 = ((l & 48) | (wq - 16 * cw)) * 4;
        #pragma unroll
        for (int m = 0; m < 2; ++m)
            #pragma unroll
            for (int r = 0; r < 4; ++r) {
                float g  = __int_as_float(__builtin_amdgcn_ds_bpermute(sl4, __float_as_int(G[m][r])));
                float vv = __int_as_float(__builtin_amdgcn_ds_bpermute(sl4, __float_as_int(aS1[3][m][r])));
                int e = 16 * (2 * rw + m) + 4 * lk + r;
                float o = g * (vv * X2[68 * (1 + i) + e] + aA[nt][m][r] * X2[e]);
                out[(e0b + e) * 320 + 128 + n] = o;
            }
    }
}

// ---------------------------------------------------------------- launch
extern "C" void kernel_launch(void* const* d_in, const int* in_sizes, int n_in,
                              void* d_out, int out_size, void* d_ws, size_t ws_size,
                              hipStream_t stream) {
    const float* fea_in1 = (const float*)d_in[0];
    const float* fea_in2 = (const float*)d_in[1];
    const float* fea_w   = (const float*)d_in[2];
    // d_in[3] = batch_edge (unused by reference)
    const float* w1_p0 = (const float*)d_in[4];
    const float* w2_p0 = (const float*)d_in[5];
    const float* w1_p1 = (const float*)d_in[6];
    const float* w2_p1 = (const float*)d_in[7];
    const float* w1_p2 = (const float*)d_in[8];
    const float* w2_p2 = (const float*)d_in[9];
    const float* w1_p3 = (const float*)d_in[10];
    const float* w2_p3 = (const float*)d_in[11];
    const float* w1_p4 = (const float*)d_in[12];
    const float* w2_p4 = (const float*)d_in[13];
    const float* w1_p5 = (const float*)d_in[14];
    const float* w2_p5 = (const float*)d_in[15];
    const float* fc_w0 = (const float*)d_in[16];
    const float* fc_b0 = (const float*)d_in[17];
    const float* fc_w1 = (const float*)d_in[18];
    const float* fc_b1 = (const float*)d_in[19];
    const float* fc_w2 = (const float*)d_in[20];
    const float* fc_b2 = (const float*)d_in[21];

    const int E = in_sizes[0] / 320;   // 200000

    u16* W = (u16*)d_ws;               // 212992 u16 = 416 KB
    float* out = (float*)d_out;

    prep_weights<<<832, 256, 0, stream>>>(w1_p0, w2_p0, w1_p1, w2_p1, w1_p2, w2_p2,
                                          w1_p3, w2_p3, w1_p4, w2_p4, w1_p5, w2_p5,
                                          fc_w0, fc_w1, fc_w2, W);
    fused_kernel<<<E / 64, 512, 0, stream>>>(fea_in1, fea_in2, fea_w,
                                             fc_b0, fc_b1, fc_b2, W, out);
}

// Round 7
// 677.230 us; speedup vs baseline: 3.5977x; 1.0506x over previous
//
#include <hip/hip_runtime.h>

// EquiConv fully-fused pipeline (round 8): MFMA split-bf16, small blocks.
// E = 200000, MUL_S = 128, MUL_V = 64, FC_IN = 128, FC_HID = 64, LEN_W = 192.
//
// Round-7 structure (all matmuls on 16x16x32 bf16 MFMA, hi+lo split = 3
// K-passes, fragment-ordered weights) with three changes aimed at the
// diagnosed latency-bubble bottleneck (all pipes <30% busy, 2 barrier-locked
// blocks/CU):
//   1. 256-thread blocks (32 edges, 4 waves): same per-wave work, but 4
//      INDEPENDENT blocks co-resident per CU -> barriers overlap.
//   2. A3 computed as 3 per-i GEMMs [32x64]@Wp3[64x64] (B shared over i)
//      instead of the 192x192 block-diagonal expansion: A3 MFMA 108->36,
//      WP region 144KB->16KB, and gate/vcoef/A3 all land in w-per-lane
//      layout -> the 48 ds_bpermute/thread epilogue is GONE.
//   3. d[e][u] computed from fp32 global xv early (hidden under fw staging),
//      kept in 8 regs, split-written to B2 once.
// LDS 26.7KB: B1 8704 u16 (x1s/fw pitch 272; 2x xv-i bufs pitch 136),
//             B2 4352 u16 (h0/h1/d pitch 136), X2 [4][32] f32.
//
// MFMA layouts (gfx950, verified rounds 6-7):
//   A-frag: lane holds A[row = l&15][k = 32*ks + 8*(l>>4) + j]
//   B-frag: lane holds B[k][col = l&15] from fragment-ordered storage
//   C/D  : col = l&15, row = 4*(l>>4) + reg
//
// ws (u16): WB 0 (65536) | W0 65536 (16384) | W1 81920 (8192)
//           W2 90112 (24576) | WP3 114688 (8192) | WD 122880 (24576)

typedef short bf16x8 __attribute__((ext_vector_type(8)));
typedef float f32x4 __attribute__((ext_vector_type(4)));
typedef unsigned short u16;
typedef unsigned short u16x4 __attribute__((ext_vector_type(4)));

#define MFMA16(a, b, c) __builtin_amdgcn_mfma_f32_16x16x32_bf16((a), (b), (c), 0, 0, 0)

__device__ __forceinline__ u16 f2bf(float x) {
    unsigned u = __float_as_uint(x);
    u += 0x7FFFu + ((u >> 16) & 1u);
    return (u16)(u >> 16);
}
__device__ __forceinline__ float bf2f(u16 h) {
    return __uint_as_float(((unsigned)h) << 16);
}
__device__ __forceinline__ float sigmoidf_(float x) { return 1.0f / (1.0f + __expf(-x)); }

__device__ __forceinline__ void split_wr(u16* hip, u16* lop, float4 v) {
    u16x4 h, lo;
    h.x = f2bf(v.x); h.y = f2bf(v.y); h.z = f2bf(v.z); h.w = f2bf(v.w);
    lo.x = f2bf(v.x - bf2f(h.x)); lo.y = f2bf(v.y - bf2f(h.y));
    lo.z = f2bf(v.z - bf2f(h.z)); lo.w = f2bf(v.w - bf2f(h.w));
    *(u16x4*)hip = h;
    *(u16x4*)lop = lo;
}

// ---------------------------------------------------------------- prep
// Fragment-ordered split weights: flat = ((nt*KB2 + kb)*64 + lane)*8 + j;
// n = 16*nt + (lane&15); k = 32*(kb mod KS) + 8*(lane>>4) + j; kb<KS -> hi.
__global__ __launch_bounds__(256) void prep_weights(
    const float* __restrict__ w1_p0, const float* __restrict__ w2_p0,
    const float* __restrict__ w1_p1, const float* __restrict__ w2_p1,
    const float* __restrict__ w1_p2, const float* __restrict__ w2_p2,
    const float* __restrict__ w1_p3, const float* __restrict__ w2_p3,
    const float* __restrict__ w1_p4, const float* __restrict__ w2_p4,
    const float* __restrict__ w1_p5, const float* __restrict__ w2_p5,
    const float* __restrict__ fc_w0, const float* __restrict__ fc_w1,
    const float* __restrict__ fc_w2,
    u16* __restrict__ W)
{
    const float INV_S = 0.08838834764831845f;   // 1/sqrt(128)
    const float INV_V = 0.125f;                 // 1/sqrt(64)
    const float SQ2   = 0.7071067811865476f;
    const float SQ3   = 0.5773502691896258f;
    int gid = blockIdx.x * 256 + threadIdx.x;
    if (gid >= 147456) return;
    float w = 0.f;
    int islo = 0;
    if (gid < 65536) {                       // WB: N=256 K=128 (Wbig)
        int g = gid, j = g & 7, ll = (g >> 3) & 63, rest = g >> 9;
        int kb = rest & 7, nt = rest >> 3;
        int n = nt * 16 + (ll & 15);
        islo = (kb >= 4);
        int k = 32 * (kb & 3) + 8 * (ll >> 4) + j;
        if (n < 128)      w = w1_p0[k * 128 + n] * w2_p0[n];
        else if (n < 192) w = w1_p1[k * 64 + (n - 128)] * w2_p1[n - 128];
        else              w = w1_p2[k * 64 + (n - 192)] * w2_p2[n - 192];
        w *= (INV_S * SQ2);
    } else if (gid < 81920) {                // W0: N=64 K=128
        int g = gid - 65536, j = g & 7, ll = (g >> 3) & 63, rest = g >> 9;
        int kb = rest & 7, nt = rest >> 3;
        int n = nt * 16 + (ll & 15);
        islo = (kb >= 4);
        int k = 32 * (kb & 3) + 8 * (ll >> 4) + j;
        w = fc_w0[k * 64 + n];
    } else if (gid < 90112) {                // W1: N=64 K=64
        int g = gid - 81920, j = g & 7, ll = (g >> 3) & 63, rest = g >> 9;
        int kb = rest & 3, nt = rest >> 2;
        int n = nt * 16 + (ll & 15);
        islo = (kb >= 2);
        int k = 32 * (kb & 1) + 8 * (ll >> 4) + j;
        w = fc_w1[k * 64 + n];
    } else if (gid < 114688) {               // W2: N=192 K=64
        int g = gid - 90112, j = g & 7, ll = (g >> 3) & 63, rest = g >> 9;
        int kb = rest & 3, nt = rest >> 2;
        int n = nt * 16 + (ll & 15);
        islo = (kb >= 2);
        int k = 32 * (kb & 1) + 8 * (ll >> 4) + j;
        w = fc_w2[k * 192 + n];
    } else if (gid < 122880) {               // WP3: N=64(w) K=64(u), w1_p3 scaled
        int g = gid - 114688, j = g & 7, ll = (g >> 3) & 63, rest = g >> 9;
        int kb = rest & 3, nt = rest >> 2;
        int n = nt * 16 + (ll & 15);
        islo = (kb >= 2);
        int k = 32 * (kb & 1) + 8 * (ll >> 4) + j;
        w = w1_p3[k * 64 + n] * w2_p3[n] * (INV_V * SQ2);
    } else {                                 // WD: N=192 K=64 (Wd)
        int g = gid - 122880, j = g & 7, ll = (g >> 3) & 63, rest = g >> 9;
        int kb = rest & 3, nt = rest >> 2;
        int n = nt * 16 + (ll & 15);
        islo = (kb >= 2);
        int k = 32 * (kb & 1) + 8 * (ll >> 4) + j;
        w = (n < 128 ? w1_p4[k * 128 + n] * w2_p4[n]
                     : w1_p5[k * 64 + (n - 128)] * w2_p5[n - 128]) * (INV_V * SQ3 * SQ2);
    }
    u16 h = f2bf(w);
    W[gid] = islo ? f2bf(w - bf2f(h)) : h;
}

// ---------------------------------------------------------------- fused
__global__ __launch_bounds__(256, 4) void fused_kernel(
    const float* __restrict__ fea_in1, const float* __restrict__ fea_in2,
    const float* __restrict__ fea_w,
    const float* __restrict__ fc_b0, const float* __restrict__ fc_b1,
    const float* __restrict__ fc_b2,
    const u16* __restrict__ Wg,
    float* __restrict__ out)
{
    __shared__ __align__(16) u16 SM[13312];      // 26624 B
    u16* B1 = SM;                 // 8704: x1s/fw [32][272]; xv bufs 2x[32][136]
    u16* B2 = SM + 8704;          // 4352: h0/h1/d [32][136]
    float* X2 = (float*)(SM + 13056);  // [4][32]

    const int t   = threadIdx.x;
    const int l   = t & 63;
    const int cw  = t >> 6;       // wave id 0..3 (column wave)
    const int lm  = l & 15;
    const int lk  = l >> 4;
    const int lk8 = lk * 8;
    const long e0b = (long)blockIdx.x * 32;

    // ---- P1: stage x2 (transposed) + split x1s
    if (t < 32) {
        float4 v = *(const float4*)(fea_in2 + (e0b + t) * 4);
        X2[t] = v.x; X2[32 + t] = v.y; X2[64 + t] = v.z; X2[96 + t] = v.w;
    }
    #pragma unroll
    for (int r = 0; r < 4; ++r) {
        int f = t + r * 256, ee = f >> 5, c4 = f & 31;
        float4 v = *(const float4*)(fea_in1 + (e0b + ee) * 320 + c4 * 4);
        split_wr(&B1[ee * 272 + c4 * 4], &B1[ee * 272 + 128 + c4 * 4], v);
    }
    __syncthreads();

    // ---- P2: S1 = x1s @ Wbig -> scal(2 tiles) gate(1) vcoef(1); 96 MFMA
    f32x4 aS1[4][2] = {};
    {
        const int ctn[4] = {2 * cw, 2 * cw + 1, 8 + cw, 12 + cw};
        const u16* bp[4];
        #pragma unroll
        for (int c = 0; c < 4; ++c) bp[c] = Wg + (ctn[c] * 8) * 512 + l * 8;
        const u16* a0p = B1 + lm * 272 + lk8;
        const u16* a1p = B1 + (16 + lm) * 272 + lk8;
        #pragma unroll 1
        for (int pass = 0; pass < 3; ++pass) {
            const int ao  = (pass == 1) ? 128 : 0;
            const int kb0 = (pass == 2) ? 4 : 0;
            #pragma unroll
            for (int ks = 0; ks < 4; ++ks) {
                bf16x8 a0 = *(const bf16x8*)(a0p + ao + 32 * ks);
                bf16x8 a1 = *(const bf16x8*)(a1p + ao + 32 * ks);
                #pragma unroll
                for (int c = 0; c < 4; ++c) {
                    bf16x8 b = *(const bf16x8*)(bp[c] + (kb0 + ks) * 512);
                    aS1[c][0] = MFMA16(a0, b, aS1[c][0]);
                    aS1[c][1] = MFMA16(a1, b, aS1[c][1]);
                }
            }
        }
    }
    // fold x2s into scal+gate tiles (NOT vcoef)
    #pragma unroll
    for (int m = 0; m < 2; ++m)
        #pragma unroll
        for (int r = 0; r < 4; ++r) {
            float xs = X2[16 * m + 4 * lk + r];
            aS1[0][m][r] *= xs;
            aS1[1][m][r] *= xs;
            aS1[2][m][r] *= xs;
        }
    __syncthreads();                          // x1s reads done

    // ---- P3: stage fw over B1; d[e][u] from fp32 global xv (8 regs)
    #pragma unroll
    for (int r = 0; r < 4; ++r) {
        int f = t + r * 256, ee = f >> 5, c4 = f & 31;
        float4 v = *(const float4*)(fea_w + (e0b + ee) * 128 + c4 * 4);
        split_wr(&B1[ee * 272 + c4 * 4], &B1[ee * 272 + 128 + c4 * 4], v);
    }
    float d8[8];
    {
        int de = t & 31, u0 = 8 * (t >> 5);
        const float* p = fea_in1 + (e0b + de) * 320 + 128 + 3 * u0;
        float4 qa = *(const float4*)(p +  0), qb = *(const float4*)(p +  4);
        float4 qc = *(const float4*)(p +  8), qd = *(const float4*)(p + 12);
        float4 qe = *(const float4*)(p + 16), qf = *(const float4*)(p + 20);
        float c1 = X2[32 + de], c2 = X2[64 + de], c3 = X2[96 + de];
        d8[0] = qa.x * c1 + qa.y * c2 + qa.z * c3;
        d8[1] = qa.w * c1 + qb.x * c2 + qb.y * c3;
        d8[2] = qb.z * c1 + qb.w * c2 + qc.x * c3;
        d8[3] = qc.y * c1 + qc.z * c2 + qc.w * c3;
        d8[4] = qd.x * c1 + qd.y * c2 + qd.z * c3;
        d8[5] = qd.w * c1 + qe.x * c2 + qe.y * c3;
        d8[6] = qe.z * c1 + qe.w * c2 + qf.x * c3;
        d8[7] = qf.y * c1 + qf.z * c2 + qf.w * c3;
    }
    __syncthreads();

    // xv i-tile stager: 32 rows x 64 u, stride-12B gather (L1-hot after P3)
    auto stage_xv = [&](int i, u16* buf) {
        int ee = t >> 3, u0 = 8 * (t & 7);
        const float* p = fea_in1 + (e0b + ee) * 320 + 128 + i + 3 * u0;
        bf16x8 hv, lv;
        #pragma unroll
        for (int q = 0; q < 8; ++q) {
            float v = p[3 * q];
            u16 h = f2bf(v);
            hv[q] = (short)h;
            lv[q] = (short)f2bf(v - bf2f(h));
        }
        *(bf16x8*)&buf[ee * 136 + u0]      = hv;
        *(bf16x8*)&buf[ee * 136 + 64 + u0] = lv;
    };

    // ---- P4: FC0 = fw @ w0; 24 MFMA; h0 -> B2
    f32x4 aF[2] = {};
    {
        const u16* bp = Wg + 65536 + (cw * 8) * 512 + l * 8;
        const u16* a0p = B1 + lm * 272 + lk8;
        const u16* a1p = B1 + (16 + lm) * 272 + lk8;
        #pragma unroll 1
        for (int pass = 0; pass < 3; ++pass) {
            const int ao  = (pass == 1) ? 128 : 0;
            const int kb0 = (pass == 2) ? 4 : 0;
            #pragma unroll
            for (int ks = 0; ks < 4; ++ks) {
                bf16x8 a0 = *(const bf16x8*)(a0p + ao + 32 * ks);
                bf16x8 a1 = *(const bf16x8*)(a1p + ao + 32 * ks);
                bf16x8 b = *(const bf16x8*)(bp + (kb0 + ks) * 512);
                aF[0] = MFMA16(a0, b, aF[0]);
                aF[1] = MFMA16(a1, b, aF[1]);
            }
        }
    }
    {
        float bb = fc_b0[16 * cw + lm];
        #pragma unroll
        for (int m = 0; m < 2; ++m)
            #pragma unroll
            for (int r = 0; r < 4; ++r) {
                float z = aF[m][r] + bb;
                float s = z * sigmoidf_(z);
                int e = 16 * m + 4 * lk + r;
                u16 hh = f2bf(s);
                B2[e * 136 + 16 * cw + lm] = hh;
                B2[e * 136 + 64 + 16 * cw + lm] = f2bf(s - bf2f(hh));
            }
    }
    __syncthreads();                          // h0 ready; fw reads done

    // ---- P5: FC1 (regs only) || stage xv-i0 -> buf0 (B1 free)
    f32x4 aH[2] = {};
    {
        const u16* bp = Wg + 81920 + (cw * 4) * 512 + l * 8;
        const u16* a0p = B2 + lm * 136 + lk8;
        const u16* a1p = B2 + (16 + lm) * 136 + lk8;
        #pragma unroll 1
        for (int pass = 0; pass < 3; ++pass) {
            const int ao  = (pass == 1) ? 64 : 0;
            const int kb0 = (pass == 2) ? 2 : 0;
            #pragma unroll
            for (int ks = 0; ks < 2; ++ks) {
                bf16x8 a0 = *(const bf16x8*)(a0p + ao + 32 * ks);
                bf16x8 a1 = *(const bf16x8*)(a1p + ao + 32 * ks);
                bf16x8 b = *(const bf16x8*)(bp + (kb0 + ks) * 512);
                aH[0] = MFMA16(a0, b, aH[0]);
                aH[1] = MFMA16(a1, b, aH[1]);
            }
        }
    }
    stage_xv(0, B1);
    __syncthreads();                          // h0 reads done; i0 staged

    // ---- P6: h1 -> B2 || stage xv-i1 -> buf1
    {
        float bb = fc_b1[16 * cw + lm];
        #pragma unroll
        for (int m = 0; m < 2; ++m)
            #pragma unroll
            for (int r = 0; r < 4; ++r) {
                float z = aH[m][r] + bb;
                float s = z * sigmoidf_(z);
                int e = 16 * m + 4 * lk + r;
                u16 hh = f2bf(s);
                B2[e * 136 + 16 * cw + lm] = hh;
                B2[e * 136 + 64 + 16 * cw + lm] = f2bf(s - bf2f(hh));
            }
    }
    stage_xv(1, B1 + 4352);
    __syncthreads();                          // h1 ready; i1 staged

    // ---- P7: FC2 = h1 @ w2 -> Wout (scal 2 tiles + gate 1); 36 MFMA
    f32x4 aW[3][2] = {};
    {
        const int ctn[3] = {2 * cw, 2 * cw + 1, 8 + cw};
        const u16* bp[3];
        #pragma unroll
        for (int c = 0; c < 3; ++c) bp[c] = Wg + 90112 + (ctn[c] * 4) * 512 + l * 8;
        const u16* a0p = B2 + lm * 136 + lk8;
        const u16* a1p = B2 + (16 + lm) * 136 + lk8;
        #pragma unroll 1
        for (int pass = 0; pass < 3; ++pass) {
            const int ao  = (pass == 1) ? 64 : 0;
            const int kb0 = (pass == 2) ? 2 : 0;
            #pragma unroll
            for (int ks = 0; ks < 2; ++ks) {
                bf16x8 a0 = *(const bf16x8*)(a0p + ao + 32 * ks);
                bf16x8 a1 = *(const bf16x8*)(a1p + ao + 32 * ks);
                #pragma unroll
                for (int c = 0; c < 3; ++c) {
                    bf16x8 b = *(const bf16x8*)(bp[c] + (kb0 + ks) * 512);
                    aW[c][0] = MFMA16(a0, b, aW[c][0]);
                    aW[c][1] = MFMA16(a1, b, aW[c][1]);
                }
            }
        }
        float b0v = fc_b2[32 * cw + lm];
        float b1v = fc_b2[32 * cw + 16 + lm];
        float bgv = fc_b2[128 + 16 * cw + lm];
        #pragma unroll
        for (int m = 0; m < 2; ++m)
            #pragma unroll
            for (int r = 0; r < 4; ++r) {
                aW[0][m][r] += b0v;
                aW[1][m][r] += b1v;
                aW[2][m][r] += bgv;
            }
    }
    __syncthreads();                          // h1 reads done

    // ---- P8: split-write d -> B2 (overwrites h1)
    {
        int de = t & 31, u0 = 8 * (t >> 5);
        bf16x8 hv, lv;
        #pragma unroll
        for (int q = 0; q < 8; ++q) {
            u16 h = f2bf(d8[q]);
            hv[q] = (short)h;
            lv[q] = (short)f2bf(d8[q] - bf2f(h));
        }
        *(bf16x8*)&B2[de * 136 + u0]      = hv;
        *(bf16x8*)&B2[de * 136 + 64 + u0] = lv;
    }
    __syncthreads();                          // d ready

    // ---- P9: S2 = d @ Wd accumulated into aS1; scal epilogue; gates
    {
        const int ctn[3] = {2 * cw, 2 * cw + 1, 8 + cw};
        const u16* bp[3];
        #pragma unroll
        for (int c = 0; c < 3; ++c) bp[c] = Wg + 122880 + (ctn[c] * 4) * 512 + l * 8;
        const u16* a0p = B2 + lm * 136 + lk8;
        const u16* a1p = B2 + (16 + lm) * 136 + lk8;
        #pragma unroll 1
        for (int pass = 0; pass < 3; ++pass) {
            const int ao  = (pass == 1) ? 64 : 0;
            const int kb0 = (pass == 2) ? 2 : 0;
            #pragma unroll
            for (int ks = 0; ks < 2; ++ks) {
                bf16x8 a0 = *(const bf16x8*)(a0p + ao + 32 * ks);
                bf16x8 a1 = *(const bf16x8*)(a1p + ao + 32 * ks);
                #pragma unroll
                for (int c = 0; c < 3; ++c) {
                    bf16x8 b = *(const bf16x8*)(bp[c] + (kb0 + ks) * 512);
                    aS1[c][0] = MFMA16(a0, b, aS1[c][0]);
                    aS1[c][1] = MFMA16(a1, b, aS1[c][1]);
                }
            }
        }
    }
    // scal outputs (frees aS1[0..1], aW[0..1])
    #pragma unroll
    for (int c2 = 0; c2 < 2; ++c2)
        #pragma unroll
        for (int m = 0; m < 2; ++m)
            #pragma unroll
            for (int r = 0; r < 4; ++r) {
                float s = aS1[c2][m][r];
                int e = 16 * m + 4 * lk + r;
                out[(e0b + e) * 320 + 32 * cw + 16 * c2 + lm] =
                    s * sigmoidf_(s) * aW[c2][m][r];
            }
    float G[2][4];
    #pragma unroll
    for (int m = 0; m < 2; ++m)
        #pragma unroll
        for (int r = 0; r < 4; ++r)
            G[m][r] = sigmoidf_(aS1[2][m][r]) * aW[2][m][r];

    // per-i A3 GEMM + vec epilogue (lane lm == w = 16cw+lm; no bpermute)
    auto vec_phase = [&](int i, const u16* buf) {
        f32x4 aA[2] = {};
        const u16* bp = Wg + 114688 + (cw * 4) * 512 + l * 8;
        const u16* a0p = buf + lm * 136 + lk8;
        const u16* a1p = buf + (16 + lm) * 136 + lk8;
        #pragma unroll 1
        for (int pass = 0; pass < 3; ++pass) {
            const int ao  = (pass == 1) ? 64 : 0;
            const int kb0 = (pass == 2) ? 2 : 0;
            #pragma unroll
            for (int ks = 0; ks < 2; ++ks) {
                bf16x8 a0 = *(const bf16x8*)(a0p + ao + 32 * ks);
                bf16x8 a1 = *(const bf16x8*)(a1p + ao + 32 * ks);
                bf16x8 b = *(const bf16x8*)(bp + (kb0 + ks) * 512);
                aA[0] = MFMA16(a0, b, aA[0]);
                aA[1] = MFMA16(a1, b, aA[1]);
            }
        }
        #pragma unroll
        for (int m = 0; m < 2; ++m)
            #pragma unroll
            for (int r = 0; r < 4; ++r) {
                int e = 16 * m + 4 * lk + r;
                float o = G[m][r] * (aS1[3][m][r] * X2[32 * (1 + i) + e]
                                     + aA[m][r] * X2[e]);
                out[(e0b + e) * 320 + 128 + 3 * (16 * cw + lm) + i] = o;
            }
    };

    // ---- P10..P12: A3-i0 | A3-i1 || stage-i2 | A3-i2
    vec_phase(0, B1);                         // buf0 staged at P5 (no bar needed)
    __syncthreads();                          // buf0 reads done
    vec_phase(1, B1 + 4352);
    stage_xv(2, B1);
    __syncthreads();                          // i2 staged; buf1 reads done
    vec_phase(2, B1);
}

// ---------------------------------------------------------------- launch
extern "C" void kernel_launch(void* const* d_in, const int* in_sizes, int n_in,
                              void* d_out, int out_size, void* d_ws, size_t ws_size,
                              hipStream_t stream) {
    const float* fea_in1 = (const float*)d_in[0];
    const float* fea_in2 = (const float*)d_in[1];
    const float* fea_w   = (const float*)d_in[2];
    // d_in[3] = batch_edge (unused by reference)
    const float* w1_p0 = (const float*)d_in[4];
    const float* w2_p0 = (const float*)d_in[5];
    const float* w1_p1 = (const float*)d_in[6];
    const float* w2_p1 = (const float*)d_in[7];
    const float* w1_p2 = (const float*)d_in[8];
    const float* w2_p2 = (const float*)d_in[9];
    const float* w1_p3 = (const float*)d_in[10];
    const float* w2_p3 = (const float*)d_in[11];
    const float* w1_p4 = (const float*)d_in[12];
    const float* w2_p4 = (const float*)d_in[13];
    const float* w1_p5 = (const float*)d_in[14];
    const float* w2_p5 = (const float*)d_in[15];
    const float* fc_w0 = (const float*)d_in[16];
    const float* fc_b0 = (const float*)d_in[17];
    const float* fc_w1 = (const float*)d_in[18];
    const float* fc_b1 = (const float*)d_in[19];
    const float* fc_w2 = (const float*)d_in[20];
    const float* fc_b2 = (const float*)d_in[21];

    const int E = in_sizes[0] / 320;   // 200000

    u16* W = (u16*)d_ws;               // 147456 u16 = 288 KB
    float* out = (float*)d_out;

    prep_weights<<<576, 256, 0, stream>>>(w1_p0, w2_p0, w1_p1, w2_p1, w1_p2, w2_p2,
                                          w1_p3, w2_p3, w1_p4, w2_p4, w1_p5, w2_p5,
                                          fc_w0, fc_w1, fc_w2, W);
    fused_kernel<<<E / 32, 256, 0, stream>>>(fea_in1, fea_in2, fea_w,
                                             fc_b0, fc_b1, fc_b2, W, out);
}

// Round 8
// 657.099 us; speedup vs baseline: 3.7079x; 1.0306x over previous
//
#include <hip/hip_runtime.h>

// EquiConv fully-fused pipeline (round 9): MFMA split-bf16, coalesced vec store.
// E = 200000, MUL_S = 128, MUL_V = 64, FC_IN = 128, FC_HID = 64, LEN_W = 192.
//
// Identical to round 8 except the vec-output path: round 8 stored
// out[...+3w+i] per i-phase (stride-12B scatter) -> each 64B sector written
// partially 3x, L2 evictions between passes -> WRITE_SIZE 443 MB vs 256 MB
// output. Now the three A3 i-phases accumulate into vo[3][2][4] registers;
// after the last phase the block's [32][192] vec section is bounced through
// LDS (pitch 196 floats: float4-aligned reads, 2-way write conflicts = free)
// and stored with fully-coalesced float4 writes.
//
// MFMA layouts (gfx950, verified rounds 6-8):
//   A-frag: lane holds A[row = l&15][k = 32*ks + 8*(l>>4) + j]
//   B-frag: lane holds B[k][col = l&15] from fragment-ordered storage
//   C/D  : col = l&15, row = 4*(l>>4) + reg
//
// ws (u16): WB 0 (65536) | W0 65536 (16384) | W1 81920 (8192)
//           W2 90112 (24576) | WP3 114688 (8192) | WD 122880 (24576)

typedef short bf16x8 __attribute__((ext_vector_type(8)));
typedef float f32x4 __attribute__((ext_vector_type(4)));
typedef unsigned short u16;
typedef unsigned short u16x4 __attribute__((ext_vector_type(4)));

#define MFMA16(a, b, c) __builtin_amdgcn_mfma_f32_16x16x32_bf16((a), (b), (c), 0, 0, 0)

__device__ __forceinline__ u16 f2bf(float x) {
    unsigned u = __float_as_uint(x);
    u += 0x7FFFu + ((u >> 16) & 1u);
    return (u16)(u >> 16);
}
__device__ __forceinline__ float bf2f(u16 h) {
    return __uint_as_float(((unsigned)h) << 16);
}
__device__ __forceinline__ float sigmoidf_(float x) { return 1.0f / (1.0f + __expf(-x)); }

__device__ __forceinline__ void split_wr(u16* hip, u16* lop, float4 v) {
    u16x4 h, lo;
    h.x = f2bf(v.x); h.y = f2bf(v.y); h.z = f2bf(v.z); h.w = f2bf(v.w);
    lo.x = f2bf(v.x - bf2f(h.x)); lo.y = f2bf(v.y - bf2f(h.y));
    lo.z = f2bf(v.z - bf2f(h.z)); lo.w = f2bf(v.w - bf2f(h.w));
    *(u16x4*)hip = h;
    *(u16x4*)lop = lo;
}

// ---------------------------------------------------------------- prep
// Fragment-ordered split weights: flat = ((nt*KB2 + kb)*64 + lane)*8 + j;
// n = 16*nt + (lane&15); k = 32*(kb mod KS) + 8*(lane>>4) + j; kb<KS -> hi.
__global__ __launch_bounds__(256) void prep_weights(
    const float* __restrict__ w1_p0, const float* __restrict__ w2_p0,
    const float* __restrict__ w1_p1, const float* __restrict__ w2_p1,
    const float* __restrict__ w1_p2, const float* __restrict__ w2_p2,
    const float* __restrict__ w1_p3, const float* __restrict__ w2_p3,
    const float* __restrict__ w1_p4, const float* __restrict__ w2_p4,
    const float* __restrict__ w1_p5, const float* __restrict__ w2_p5,
    const float* __restrict__ fc_w0, const float* __restrict__ fc_w1,
    const float* __restrict__ fc_w2,
    u16* __restrict__ W)
{
    const float INV_S = 0.08838834764831845f;   // 1/sqrt(128)
    const float INV_V = 0.125f;                 // 1/sqrt(64)
    const float SQ2   = 0.7071067811865476f;
    const float SQ3   = 0.5773502691896258f;
    int gid = blockIdx.x * 256 + threadIdx.x;
    if (gid >= 147456) return;
    float w = 0.f;
    int islo = 0;
    if (gid < 65536) {                       // WB: N=256 K=128 (Wbig)
        int g = gid, j = g & 7, ll = (g >> 3) & 63, rest = g >> 9;
        int kb = rest & 7, nt = rest >> 3;
        int n = nt * 16 + (ll & 15);
        islo = (kb >= 4);
        int k = 32 * (kb & 3) + 8 * (ll >> 4) + j;
        if (n < 128)      w = w1_p0[k * 128 + n] * w2_p0[n];
        else if (n < 192) w = w1_p1[k * 64 + (n - 128)] * w2_p1[n - 128];
        else              w = w1_p2[k * 64 + (n - 192)] * w2_p2[n - 192];
        w *= (INV_S * SQ2);
    } else if (gid < 81920) {                // W0: N=64 K=128
        int g = gid - 65536, j = g & 7, ll = (g >> 3) & 63, rest = g >> 9;
        int kb = rest & 7, nt = rest >> 3;
        int n = nt * 16 + (ll & 15);
        islo = (kb >= 4);
        int k = 32 * (kb & 3) + 8 * (ll >> 4) + j;
        w = fc_w0[k * 64 + n];
    } else if (gid < 90112) {                // W1: N=64 K=64
        int g = gid - 81920, j = g & 7, ll = (g >> 3) & 63, rest = g >> 9;
        int kb = rest & 3, nt = rest >> 2;
        int n = nt * 16 + (ll & 15);
        islo = (kb >= 2);
        int k = 32 * (kb & 1) + 8 * (ll >> 4) + j;
        w = fc_w1[k * 64 + n];
    } else if (gid < 114688) {               // W2: N=192 K=64
        int g = gid - 90112, j = g & 7, ll = (g >> 3) & 63, rest = g >> 9;
        int kb = rest & 3, nt = rest >> 2;
        int n = nt * 16 + (ll & 15);
        islo = (kb >= 2);
        int k = 32 * (kb & 1) + 8 * (ll >> 4) + j;
        w = fc_w2[k * 192 + n];
    } else if (gid < 122880) {               // WP3: N=64(w) K=64(u), w1_p3 scaled
        int g = gid - 114688, j = g & 7, ll = (g >> 3) & 63, rest = g >> 9;
        int kb = rest & 3, nt = rest >> 2;
        int n = nt * 16 + (ll & 15);
        islo = (kb >= 2);
        int k = 32 * (kb & 1) + 8 * (ll >> 4) + j;
        w = w1_p3[k * 64 + n] * w2_p3[n] * (INV_V * SQ2);
    } else {                                 // WD: N=192 K=64 (Wd)
        int g = gid - 122880, j = g & 7, ll = (g >> 3) & 63, rest = g >> 9;
        int kb = rest & 3, nt = rest >> 2;
        int n = nt * 16 + (ll & 15);
        islo = (kb >= 2);
        int k = 32 * (kb & 1) + 8 * (ll >> 4) + j;
        w = (n < 128 ? w1_p4[k * 128 + n] * w2_p4[n]
                     : w1_p5[k * 64 + (n - 128)] * w2_p5[n - 128]) * (INV_V * SQ3 * SQ2);
    }
    u16 h = f2bf(w);
    W[gid] = islo ? f2bf(w - bf2f(h)) : h;
}

// ---------------------------------------------------------------- fused
__global__ __launch_bounds__(256, 4) void fused_kernel(
    const float* __restrict__ fea_in1, const float* __restrict__ fea_in2,
    const float* __restrict__ fea_w,
    const float* __restrict__ fc_b0, const float* __restrict__ fc_b1,
    const float* __restrict__ fc_b2,
    const u16* __restrict__ Wg,
    float* __restrict__ out)
{
    __shared__ __align__(16) u16 SM[13312];      // 26624 B
    u16* B1 = SM;                 // 8704: x1s/fw [32][272]; xv bufs 2x[32][136]
    u16* B2 = SM + 8704;          // 4352: h0/h1/d [32][136]
    float* X2 = (float*)(SM + 13056);  // [4][32] (bytes 26112.. -- outside bounce)
    float* OB = (float*)SM;       // vec-out bounce [32][196] floats (25088 B)

    const int t   = threadIdx.x;
    const int l   = t & 63;
    const int cw  = t >> 6;       // wave id 0..3 (column wave)
    const int lm  = l & 15;
    const int lk  = l >> 4;
    const int lk8 = lk * 8;
    const long e0b = (long)blockIdx.x * 32;

    // ---- P1: stage x2 (transposed) + split x1s
    if (t < 32) {
        float4 v = *(const float4*)(fea_in2 + (e0b + t) * 4);
        X2[t] = v.x; X2[32 + t] = v.y; X2[64 + t] = v.z; X2[96 + t] = v.w;
    }
    #pragma unroll
    for (int r = 0; r < 4; ++r) {
        int f = t + r * 256, ee = f >> 5, c4 = f & 31;
        float4 v = *(const float4*)(fea_in1 + (e0b + ee) * 320 + c4 * 4);
        split_wr(&B1[ee * 272 + c4 * 4], &B1[ee * 272 + 128 + c4 * 4], v);
    }
    __syncthreads();

    // ---- P2: S1 = x1s @ Wbig -> scal(2 tiles) gate(1) vcoef(1); 96 MFMA
    f32x4 aS1[4][2] = {};
    {
        const int ctn[4] = {2 * cw, 2 * cw + 1, 8 + cw, 12 + cw};
        const u16* bp[4];
        #pragma unroll
        for (int c = 0; c < 4; ++c) bp[c] = Wg + (ctn[c] * 8) * 512 + l * 8;
        const u16* a0p = B1 + lm * 272 + lk8;
        const u16* a1p = B1 + (16 + lm) * 272 + lk8;
        #pragma unroll 1
        for (int pass = 0; pass < 3; ++pass) {
            const int ao  = (pass == 1) ? 128 : 0;
            const int kb0 = (pass == 2) ? 4 : 0;
            #pragma unroll
            for (int ks = 0; ks < 4; ++ks) {
                bf16x8 a0 = *(const bf16x8*)(a0p + ao + 32 * ks);
                bf16x8 a1 = *(const bf16x8*)(a1p + ao + 32 * ks);
                #pragma unroll
                for (int c = 0; c < 4; ++c) {
                    bf16x8 b = *(const bf16x8*)(bp[c] + (kb0 + ks) * 512);
                    aS1[c][0] = MFMA16(a0, b, aS1[c][0]);
                    aS1[c][1] = MFMA16(a1, b, aS1[c][1]);
                }
            }
        }
    }
    // fold x2s into scal+gate tiles (NOT vcoef)
    #pragma unroll
    for (int m = 0; m < 2; ++m)
        #pragma unroll
        for (int r = 0; r < 4; ++r) {
            float xs = X2[16 * m + 4 * lk + r];
            aS1[0][m][r] *= xs;
            aS1[1][m][r] *= xs;
            aS1[2][m][r] *= xs;
        }
    __syncthreads();                          // x1s reads done

    // ---- P3: stage fw over B1; d[e][u] from fp32 global xv (8 regs)
    #pragma unroll
    for (int r = 0; r < 4; ++r) {
        int f = t + r * 256, ee = f >> 5, c4 = f & 31;
        float4 v = *(const float4*)(fea_w + (e0b + ee) * 128 + c4 * 4);
        split_wr(&B1[ee * 272 + c4 * 4], &B1[ee * 272 + 128 + c4 * 4], v);
    }
    float d8[8];
    {
        int de = t & 31, u0 = 8 * (t >> 5);
        const float* p = fea_in1 + (e0b + de) * 320 + 128 + 3 * u0;
        float4 qa = *(const float4*)(p +  0), qb = *(const float4*)(p +  4);
        float4 qc = *(const float4*)(p +  8), qd = *(const float4*)(p + 12);
        float4 qe = *(const float4*)(p + 16), qf = *(const float4*)(p + 20);
        float c1 = X2[32 + de], c2 = X2[64 + de], c3 = X2[96 + de];
        d8[0] = qa.x * c1 + qa.y * c2 + qa.z * c3;
        d8[1] = qa.w * c1 + qb.x * c2 + qb.y * c3;
        d8[2] = qb.z * c1 + qb.w * c2 + qc.x * c3;
        d8[3] = qc.y * c1 + qc.z * c2 + qc.w * c3;
        d8[4] = qd.x * c1 + qd.y * c2 + qd.z * c3;
        d8[5] = qd.w * c1 + qe.x * c2 + qe.y * c3;
        d8[6] = qe.z * c1 + qe.w * c2 + qf.x * c3;
        d8[7] = qf.y * c1 + qf.z * c2 + qf.w * c3;
    }
    __syncthreads();

    // xv i-tile stager: 32 rows x 64 u, stride-12B gather (L1/L2-hot after P3)
    auto stage_xv = [&](int i, u16* buf) {
        int ee = t >> 3, u0 = 8 * (t & 7);
        const float* p = fea_in1 + (e0b + ee) * 320 + 128 + i + 3 * u0;
        bf16x8 hv, lv;
        #pragma unroll
        for (int q = 0; q < 8; ++q) {
            float v = p[3 * q];
            u16 h = f2bf(v);
            hv[q] = (short)h;
            lv[q] = (short)f2bf(v - bf2f(h));
        }
        *(bf16x8*)&buf[ee * 136 + u0]      = hv;
        *(bf16x8*)&buf[ee * 136 + 64 + u0] = lv;
    };

    // ---- P4: FC0 = fw @ w0; 24 MFMA; h0 -> B2
    f32x4 aF[2] = {};
    {
        const u16* bp = Wg + 65536 + (cw * 8) * 512 + l * 8;
        const u16* a0p = B1 + lm * 272 + lk8;
        const u16* a1p = B1 + (16 + lm) * 272 + lk8;
        #pragma unroll 1
        for (int pass = 0; pass < 3; ++pass) {
            const int ao  = (pass == 1) ? 128 : 0;
            const int kb0 = (pass == 2) ? 4 : 0;
            #pragma unroll
            for (int ks = 0; ks < 4; ++ks) {
                bf16x8 a0 = *(const bf16x8*)(a0p + ao + 32 * ks);
                bf16x8 a1 = *(const bf16x8*)(a1p + ao + 32 * ks);
                bf16x8 b = *(const bf16x8*)(bp + (kb0 + ks) * 512);
                aF[0] = MFMA16(a0, b, aF[0]);
                aF[1] = MFMA16(a1, b, aF[1]);
            }
        }
    }
    {
        float bb = fc_b0[16 * cw + lm];
        #pragma unroll
        for (int m = 0; m < 2; ++m)
            #pragma unroll
            for (int r = 0; r < 4; ++r) {
                float z = aF[m][r] + bb;
                float s = z * sigmoidf_(z);
                int e = 16 * m + 4 * lk + r;
                u16 hh = f2bf(s);
                B2[e * 136 + 16 * cw + lm] = hh;
                B2[e * 136 + 64 + 16 * cw + lm] = f2bf(s - bf2f(hh));
            }
    }
    __syncthreads();                          // h0 ready; fw reads done

    // ---- P5: FC1 (regs only) || stage xv-i0 -> buf0 (B1 free)
    f32x4 aH[2] = {};
    {
        const u16* bp = Wg + 81920 + (cw * 4) * 512 + l * 8;
        const u16* a0p = B2 + lm * 136 + lk8;
        const u16* a1p = B2 + (16 + lm) * 136 + lk8;
        #pragma unroll 1
        for (int pass = 0; pass < 3; ++pass) {
            const int ao  = (pass == 1) ? 64 : 0;
            const int kb0 = (pass == 2) ? 2 : 0;
            #pragma unroll
            for (int ks = 0; ks < 2; ++ks) {
                bf16x8 a0 = *(const bf16x8*)(a0p + ao + 32 * ks);
                bf16x8 a1 = *(const bf16x8*)(a1p + ao + 32 * ks);
                bf16x8 b = *(const bf16x8*)(bp + (kb0 + ks) * 512);
                aH[0] = MFMA16(a0, b, aH[0]);
                aH[1] = MFMA16(a1, b, aH[1]);
            }
        }
    }
    stage_xv(0, B1);
    __syncthreads();                          // h0 reads done; i0 staged

    // ---- P6: h1 -> B2 || stage xv-i1 -> buf1
    {
        float bb = fc_b1[16 * cw + lm];
        #pragma unroll
        for (int m = 0; m < 2; ++m)
            #pragma unroll
            for (int r = 0; r < 4; ++r) {
                float z = aH[m][r] + bb;
                float s = z * sigmoidf_(z);
                int e = 16 * m + 4 * lk + r;
                u16 hh = f2bf(s);
                B2[e * 136 + 16 * cw + lm] = hh;
                B2[e * 136 + 64 + 16 * cw + lm] = f2bf(s - bf2f(hh));
            }
    }
    stage_xv(1, B1 + 4352);
    __syncthreads();                          // h1 ready; i1 staged

    // ---- P7: FC2 = h1 @ w2 -> Wout (scal 2 tiles + gate 1); 36 MFMA
    f32x4 aW[3][2] = {};
    {
        const int ctn[3] = {2 * cw, 2 * cw + 1, 8 + cw};
        const u16* bp[3];
        #pragma unroll
        for (int c = 0; c < 3; ++c) bp[c] = Wg + 90112 + (ctn[c] * 4) * 512 + l * 8;
        const u16* a0p = B2 + lm * 136 + lk8;
        const u16* a1p = B2 + (16 + lm) * 136 + lk8;
        #pragma unroll 1
        for (int pass = 0; pass < 3; ++pass) {
            const int ao  = (pass == 1) ? 64 : 0;
            const int kb0 = (pass == 2) ? 2 : 0;
            #pragma unroll
            for (int ks = 0; ks < 2; ++ks) {
                bf16x8 a0 = *(const bf16x8*)(a0p + ao + 32 * ks);
                bf16x8 a1 = *(const bf16x8*)(a1p + ao + 32 * ks);
                #pragma unroll
                for (int c = 0; c < 3; ++c) {
                    bf16x8 b = *(const bf16x8*)(bp[c] + (kb0 + ks) * 512);
                    aW[c][0] = MFMA16(a0, b, aW[c][0]);
                    aW[c][1] = MFMA16(a1, b, aW[c][1]);
                }
            }
        }
        float b0v = fc_b2[32 * cw + lm];
        float b1v = fc_b2[32 * cw + 16 + lm];
        float bgv = fc_b2[128 + 16 * cw + lm];
        #pragma unroll
        for (int m = 0; m < 2; ++m)
            #pragma unroll
            for (int r = 0; r < 4; ++r) {
                aW[0][m][r] += b0v;
                aW[1][m][r] += b1v;
                aW[2][m][r] += bgv;
            }
    }
    __syncthreads();                          // h1 reads done

    // ---- P8: split-write d -> B2 (overwrites h1)
    {
        int de = t & 31, u0 = 8 * (t >> 5);
        bf16x8 hv, lv;
        #pragma unroll
        for (int q = 0; q < 8; ++q) {
            u16 h = f2bf(d8[q]);
            hv[q] = (short)h;
            lv[q] = (short)f2bf(d8[q] - bf2f(h));
        }
        *(bf16x8*)&B2[de * 136 + u0]      = hv;
        *(bf16x8*)&B2[de * 136 + 64 + u0] = lv;
    }
    __syncthreads();                          // d ready

    // ---- P9: S2 = d @ Wd accumulated into aS1; scal epilogue; gates
    {
        const int ctn[3] = {2 * cw, 2 * cw + 1, 8 + cw};
        const u16* bp[3];
        #pragma unroll
        for (int c = 0; c < 3; ++c) bp[c] = Wg + 122880 + (ctn[c] * 4) * 512 + l * 8;
        const u16* a0p = B2 + lm * 136 + lk8;
        const u16* a1p = B2 + (16 + lm) * 136 + lk8;
        #pragma unroll 1
        for (int pass = 0; pass < 3; ++pass) {
            const int ao  = (pass == 1) ? 64 : 0;
            const int kb0 = (pass == 2) ? 2 : 0;
            #pragma unroll
            for (int ks = 0; ks < 2; ++ks) {
                bf16x8 a0 = *(const bf16x8*)(a0p + ao + 32 * ks);
                bf16x8 a1 = *(const bf16x8*)(a1p + ao + 32 * ks);
                #pragma unroll
                for (int c = 0; c < 3; ++c) {
                    bf16x8 b = *(const bf16x8*)(bp[c] + (kb0 + ks) * 512);
                    aS1[c][0] = MFMA16(a0, b, aS1[c][0]);
                    aS1[c][1] = MFMA16(a1, b, aS1[c][1]);
                }
            }
        }
    }
    // scal outputs: 64B-sector-aligned direct stores (no amplification)
    #pragma unroll
    for (int c2 = 0; c2 < 2; ++c2)
        #pragma unroll
        for (int m = 0; m < 2; ++m)
            #pragma unroll
            for (int r = 0; r < 4; ++r) {
                float s = aS1[c2][m][r];
                int e = 16 * m + 4 * lk + r;
                out[(e0b + e) * 320 + 32 * cw + 16 * c2 + lm] =
                    s * sigmoidf_(s) * aW[c2][m][r];
            }
    float G[2][4];
    #pragma unroll
    for (int m = 0; m < 2; ++m)
        #pragma unroll
        for (int r = 0; r < 4; ++r)
            G[m][r] = sigmoidf_(aS1[2][m][r]) * aW[2][m][r];

    // per-i A3 GEMM; results ACCUMULATED into vo regs (no global store here)
    float vo[3][2][4];
    auto vec_phase = [&](int i, const u16* buf) {
        f32x4 aA[2] = {};
        const u16* bp = Wg + 114688 + (cw * 4) * 512 + l * 8;
        const u16* a0p = buf + lm * 136 + lk8;
        const u16* a1p = buf + (16 + lm) * 136 + lk8;
        #pragma unroll 1
        for (int pass = 0; pass < 3; ++pass) {
            const int ao  = (pass == 1) ? 64 : 0;
            const int kb0 = (pass == 2) ? 2 : 0;
            #pragma unroll
            for (int ks = 0; ks < 2; ++ks) {
                bf16x8 a0 = *(const bf16x8*)(a0p + ao + 32 * ks);
                bf16x8 a1 = *(const bf16x8*)(a1p + ao + 32 * ks);
                bf16x8 b = *(const bf16x8*)(bp + (kb0 + ks) * 512);
                aA[0] = MFMA16(a0, b, aA[0]);
                aA[1] = MFMA16(a1, b, aA[1]);
            }
        }
        #pragma unroll
        for (int m = 0; m < 2; ++m)
            #pragma unroll
            for (int r = 0; r < 4; ++r) {
                int e = 16 * m + 4 * lk + r;
                vo[i][m][r] = G[m][r] * (aS1[3][m][r] * X2[32 * (1 + i) + e]
                                         + aA[m][r] * X2[e]);
            }
    };

    // ---- P10..P12: A3-i0 | A3-i1 || stage-i2 | A3-i2
    vec_phase(0, B1);                         // buf0 staged at P5
    __syncthreads();                          // buf0 reads done
    vec_phase(1, B1 + 4352);
    stage_xv(2, B1);
    __syncthreads();                          // i2 staged; buf1 reads done
    vec_phase(2, B1);

    // ---- P13: bounce vec outputs through LDS -> coalesced float4 stores
    __syncthreads();                          // all LDS reads done (OB aliases B1/B2)
    #pragma unroll
    for (int i = 0; i < 3; ++i)
        #pragma unroll
        for (int m = 0; m < 2; ++m)
            #pragma unroll
            for (int r = 0; r < 4; ++r) {
                int e = 16 * m + 4 * lk + r;
                OB[e * 196 + 3 * (16 * cw + lm) + i] = vo[i][m][r];
            }
    __syncthreads();
    #pragma unroll
    for (int r6 = 0; r6 < 6; ++r6) {
        int f = t + r6 * 256;                 // 1536 float4 = 32 x 192
        int row = f / 48, c4 = f - row * 48;
        float4 v = *(const float4*)&OB[row * 196 + c4 * 4];
        *(float4*)(out + (e0b + row) * 320 + 128 + c4 * 4) = v;
    }
}

// ---------------------------------------------------------------- launch
extern "C" void kernel_launch(void* const* d_in, const int* in_sizes, int n_in,
                              void* d_out, int out_size, void* d_ws, size_t ws_size,
                              hipStream_t stream) {
    const float* fea_in1 = (const float*)d_in[0];
    const float* fea_in2 = (const float*)d_in[1];
    const float* fea_w   = (const float*)d_in[2];
    // d_in[3] = batch_edge (unused by reference)
    const float* w1_p0 = (const float*)d_in[4];
    const float* w2_p0 = (const float*)d_in[5];
    const float* w1_p1 = (const float*)d_in[6];
    const float* w2_p1 = (const float*)d_in[7];
    const float* w1_p2 = (const float*)d_in[8];
    const float* w2_p2 = (const float*)d_in[9];
    const float* w1_p3 = (const float*)d_in[10];
    const float* w2_p3 = (const float*)d_in[11];
    const float* w1_p4 = (const float*)d_in[12];
    const float* w2_p4 = (const float*)d_in[13];
    const float* w1_p5 = (const float*)d_in[14];
    const float* w2_p5 = (const float*)d_in[15];
    const float* fc_w0 = (const float*)d_in[16];
    const float* fc_b0 = (const float*)d_in[17];
    const float* fc_w1 = (const float*)d_in[18];
    const float* fc_b1 = (const float*)d_in[19];
    const float* fc_w2 = (const float*)d_in[20];
    const float* fc_b2 = (const float*)d_in[21];

    const int E = in_sizes[0] / 320;   // 200000

    u16* W = (u16*)d_ws;               // 147456 u16 = 288 KB
    float* out = (float*)d_out;

    prep_weights<<<576, 256, 0, stream>>>(w1_p0, w2_p0, w1_p1, w2_p1, w1_p2, w2_p2,
                                          w1_p3, w2_p3, w1_p4, w2_p4, w1_p5, w2_p5,
                                          fc_w0, fc_w1, fc_w2, W);
    fused_kernel<<<E / 32, 256, 0, stream>>>(fea_in1, fea_in2, fea_w,
                                             fc_b0, fc_b1, fc_b2, W, out);
}